// Round 1
// baseline (14401.869 us; speedup 1.0000x reference)
//
#include <hip/hip_runtime.h>

#define N_NODES 50000
#define NE0 500000
#define NE1 300000
#define DD 64

// ---------------------------------------------------------------------------
// Dense layer: hout[f] = act(b[f] + sum_k hin[k] * w[k*64+f])
// Both loops fully unrolled: hin/hout stay in VGPRs (runtime-indexed arrays
// would spill to scratch); w/b indices are compile-time + uniform -> s_load,
// so each FMA is v_fma_f32 v,v,s (weights ride free in the SGPR operand).
// ---------------------------------------------------------------------------
template <int K, bool RELU>
__device__ __forceinline__ void layerT(const float* __restrict__ w,
                                       const float* __restrict__ b,
                                       const float* __restrict__ hin,
                                       float* __restrict__ hout) {
#pragma unroll
  for (int f = 0; f < DD; ++f) {
    float a0 = b[f], a1 = 0.f, a2 = 0.f, a3 = 0.f;
#pragma unroll
    for (int k = 0; k < K; k += 4) {
      a0 = fmaf(hin[k + 0], w[(k + 0) * DD + f], a0);
      a1 = fmaf(hin[k + 1], w[(k + 1) * DD + f], a1);
      a2 = fmaf(hin[k + 2], w[(k + 2) * DD + f], a2);
      a3 = fmaf(hin[k + 3], w[(k + 3) * DD + f], a3);
    }
    float a = (a0 + a1) + (a2 + a3);
    hout[f] = RELU ? fmaxf(a, 0.f) : a;
  }
}

// ---------------------------------------------------------------------------
__global__ void degrees_k(const int* __restrict__ src, const int* __restrict__ dst,
                          float* __restrict__ degO, float* __restrict__ degI) {
  int e = blockIdx.x * 256 + threadIdx.x;
  if (e < NE0 + NE1) {
    atomicAdd(degO + src[e], 1.0f);
    atomicAdd(degI + dst[e], 1.0f);
  }
}

// ---------------------------------------------------------------------------
__global__ __launch_bounds__(256) void node_mlp_k(
    const float* __restrict__ nf, const float* __restrict__ w0,
    const float* __restrict__ b0, const float* __restrict__ w1,
    const float* __restrict__ b1, const float* __restrict__ w2,
    const float* __restrict__ b2, float* __restrict__ hn) {
  int n = blockIdx.x * 256 + threadIdx.x;
  if (n >= N_NODES) return;
  float x[32];
#pragma unroll
  for (int i = 0; i < 32; i += 4) {
    float4 v = *reinterpret_cast<const float4*>(nf + (size_t)n * 32 + i);
    x[i] = v.x; x[i + 1] = v.y; x[i + 2] = v.z; x[i + 3] = v.w;
  }
  float h0[DD], h1[DD];
  layerT<32, true>(w0, b0, x, h0);
  layerT<64, true>(w1, b1, h0, h1);
  layerT<64, false>(w2, b2, h1, h0);  // h0 reused as output
#pragma unroll
  for (int f = 0; f < DD; f += 4) {
    *reinterpret_cast<float4*>(hn + (size_t)n * DD + f) =
        make_float4(h0[f], h0[f + 1], h0[f + 2], h0[f + 3]);
  }
}

// ---------------------------------------------------------------------------
// Fused: edge MLP (never materialized to HBM) + conv1 message + scatter-add.
// ---------------------------------------------------------------------------
template <int FIN>
__global__ __launch_bounds__(256) void edge_conv1_k(
    const float* __restrict__ ef, const float* __restrict__ w0,
    const float* __restrict__ b0, const float* __restrict__ w1,
    const float* __restrict__ b1, const float* __restrict__ w2,
    const float* __restrict__ b2, const float* __restrict__ hn,
    const int* __restrict__ src, const int* __restrict__ dst,
    const float* __restrict__ degO, const float* __restrict__ degI,
    float* __restrict__ agg1, int nE, int ebase) {
  int e = blockIdx.x * 256 + threadIdx.x;
  if (e >= nE) return;
  float x[FIN];
#pragma unroll
  for (int i = 0; i < FIN; i += 4) {
    float4 v = *reinterpret_cast<const float4*>(ef + (size_t)e * FIN + i);
    x[i] = v.x; x[i + 1] = v.y; x[i + 2] = v.z; x[i + 3] = v.w;
  }
  float h0[DD], h1[DD];
  layerT<FIN, true>(w0, b0, x, h0);
  layerT<64, true>(w1, b1, h0, h1);
  layerT<64, false>(w2, b2, h1, h0);  // h0 = he
  int ge = ebase + e;
  int s = src[ge], d = dst[ge];
  float norm = rsqrtf(fmaxf(degO[s], 1.f) * fmaxf(degI[d], 1.f));
  const float* hs = hn + (size_t)s * DD;
  const float* hd = hn + (size_t)d * DD;
  float* ag = agg1 + (size_t)d * DD;
#pragma unroll
  for (int f = 0; f < DD; f += 4) {
    float4 a = *reinterpret_cast<const float4*>(hs + f);
    float4 c = *reinterpret_cast<const float4*>(hd + f);
    atomicAdd(ag + f + 0, (h0[f + 0] + a.x + c.x) * norm);
    atomicAdd(ag + f + 1, (h0[f + 1] + a.y + c.y) * norm);
    atomicAdd(ag + f + 2, (h0[f + 2] + a.z + c.z) * norm);
    atomicAdd(ag + f + 3, (h0[f + 3] + a.w + c.w) * norm);
  }
}

// ---------------------------------------------------------------------------
// conv1 node side: h1 = relu(agg1 @ c1_w + c1_b); then collapse through c2_w
// (64->1) to a scalar s[n] (linearity of segment_sum lets conv2 scatter
// scalars). Also seeds out[n] = c2_b.
// ---------------------------------------------------------------------------
__global__ __launch_bounds__(256) void conv1_node_k(
    const float* __restrict__ agg1, const float* __restrict__ c1w,
    const float* __restrict__ c1b, const float* __restrict__ c2w,
    const float* __restrict__ c2b, float* __restrict__ sbuf,
    float* __restrict__ out) {
  int n = blockIdx.x * 256 + threadIdx.x;
  if (n >= N_NODES) return;
  float a[DD], h[DD];
#pragma unroll
  for (int f = 0; f < DD; f += 4) {
    float4 v = *reinterpret_cast<const float4*>(agg1 + (size_t)n * DD + f);
    a[f] = v.x; a[f + 1] = v.y; a[f + 2] = v.z; a[f + 3] = v.w;
  }
  layerT<64, true>(c1w, c1b, a, h);
  float s0 = 0.f, s1 = 0.f, s2 = 0.f, s3 = 0.f;
#pragma unroll
  for (int f = 0; f < DD; f += 4) {
    s0 = fmaf(h[f + 0], c2w[f + 0], s0);
    s1 = fmaf(h[f + 1], c2w[f + 1], s1);
    s2 = fmaf(h[f + 2], c2w[f + 2], s2);
    s3 = fmaf(h[f + 3], c2w[f + 3], s3);
  }
  sbuf[n] = (s0 + s1) + (s2 + s3);
  out[n] = c2b[0];
}

// ---------------------------------------------------------------------------
__global__ void conv2_edge_k(const float* __restrict__ sbuf,
                             const int* __restrict__ src,
                             const int* __restrict__ dst,
                             const float* __restrict__ degO,
                             const float* __restrict__ degI,
                             float* __restrict__ out) {
  int e = blockIdx.x * 256 + threadIdx.x;
  if (e < NE0 + NE1) {
    int s = src[e], d = dst[e];
    float norm = rsqrtf(fmaxf(degO[s], 1.f) * fmaxf(degI[d], 1.f));
    atomicAdd(out + d, norm * sbuf[s]);
  }
}

// ---------------------------------------------------------------------------
extern "C" void kernel_launch(void* const* d_in, const int* in_sizes, int n_in,
                              void* d_out, int out_size, void* d_ws,
                              size_t ws_size, hipStream_t stream) {
  const float* nf   = (const float*)d_in[0];
  const float* ef0  = (const float*)d_in[1];
  const float* ef1  = (const float*)d_in[2];
  const float* n_w0 = (const float*)d_in[3];  const float* n_b0 = (const float*)d_in[4];
  const float* n_w1 = (const float*)d_in[5];  const float* n_b1 = (const float*)d_in[6];
  const float* n_w2 = (const float*)d_in[7];  const float* n_b2 = (const float*)d_in[8];
  const float* e0w0 = (const float*)d_in[9];  const float* e0b0 = (const float*)d_in[10];
  const float* e0w1 = (const float*)d_in[11]; const float* e0b1 = (const float*)d_in[12];
  const float* e0w2 = (const float*)d_in[13]; const float* e0b2 = (const float*)d_in[14];
  const float* e1w0 = (const float*)d_in[15]; const float* e1b0 = (const float*)d_in[16];
  const float* e1w1 = (const float*)d_in[17]; const float* e1b1 = (const float*)d_in[18];
  const float* e1w2 = (const float*)d_in[19]; const float* e1b2 = (const float*)d_in[20];
  const float* c1w  = (const float*)d_in[21]; const float* c1b  = (const float*)d_in[22];
  const float* c2w  = (const float*)d_in[23]; const float* c2b  = (const float*)d_in[24];
  const int* src = (const int*)d_in[25];
  const int* dst = (const int*)d_in[26];
  float* out = (float*)d_out;

  // Workspace layout (floats): hn[3.2M] | agg1[3.2M] | degO[50K] | degI[50K] | sbuf[50K]
  float* ws   = (float*)d_ws;
  float* hn   = ws;
  float* agg1 = ws + 3200000;
  float* degO = ws + 6400000;
  float* degI = degO + N_NODES;
  float* sbuf = degI + N_NODES;

  // zero agg1 + degO + degI (contiguous region) each call
  hipMemsetAsync(agg1, 0, (size_t)(3200000 + 2 * N_NODES) * sizeof(float), stream);

  degrees_k<<<(NE0 + NE1 + 255) / 256, 256, 0, stream>>>(src, dst, degO, degI);
  node_mlp_k<<<(N_NODES + 255) / 256, 256, 0, stream>>>(nf, n_w0, n_b0, n_w1,
                                                        n_b1, n_w2, n_b2, hn);
  edge_conv1_k<16><<<(NE0 + 255) / 256, 256, 0, stream>>>(
      ef0, e0w0, e0b0, e0w1, e0b1, e0w2, e0b2, hn, src, dst, degO, degI, agg1,
      NE0, 0);
  edge_conv1_k<8><<<(NE1 + 255) / 256, 256, 0, stream>>>(
      ef1, e1w0, e1b0, e1w1, e1b1, e1w2, e1b2, hn, src, dst, degO, degI, agg1,
      NE1, NE0);
  conv1_node_k<<<(N_NODES + 255) / 256, 256, 0, stream>>>(agg1, c1w, c1b, c2w,
                                                          c2b, sbuf, out);
  conv2_edge_k<<<(NE0 + NE1 + 255) / 256, 256, 0, stream>>>(sbuf, src, dst,
                                                            degO, degI, out);
}

// Round 2
// 1696.554 us; speedup vs baseline: 8.4889x; 8.4889x over previous
//
#include <hip/hip_runtime.h>

#define N_NODES 50000
#define NE0 500000
#define NE1 300000
#define DD 64
#define LP 132  // LDS row stride (floats): 132*4=528B = 33*16 (keeps b128 align, +4 bank skew kills 8-way conflicts on transposed writes)

// ---------------------------------------------------------------------------
// Tiled dense layer, LDS->LDS (or ->regs). Input Hin[k][e] transposed in LDS.
// Thread (tx,ty) computes rows e = ty*4..ty*4+3, cols f = tx*8..tx*8+7.
// Per k: 1 ds_read_b128 (activations, broadcast across the 8 tx lanes) +
// 2 global dwordx4 (weights, shared across ty -> L1 broadcast) feed 32 FMAs.
// ---------------------------------------------------------------------------
template <int K, bool RELU, bool TO_LDS>
__device__ __forceinline__ void layer_core(
    const float (*__restrict__ Hin)[LP], float (*__restrict__ Hout)[LP],
    const float* __restrict__ W, const float* __restrict__ B,
    int tx, int ty, float (*__restrict__ accret)[8]) {
  float acc[4][8];
  float4 bv0 = *(const float4*)(B + tx * 8);
  float4 bv1 = *(const float4*)(B + tx * 8 + 4);
  const float bb[8] = {bv0.x, bv0.y, bv0.z, bv0.w, bv1.x, bv1.y, bv1.z, bv1.w};
#pragma unroll
  for (int i = 0; i < 4; ++i)
#pragma unroll
    for (int j = 0; j < 8; ++j) acc[i][j] = bb[j];
#pragma unroll 8
  for (int k = 0; k < K; ++k) {
    float4 a = *(const float4*)(&Hin[k][ty * 4]);
    float4 w0 = *(const float4*)(W + k * 64 + tx * 8);
    float4 w1 = *(const float4*)(W + k * 64 + tx * 8 + 4);
    const float av[4] = {a.x, a.y, a.z, a.w};
    const float wv[8] = {w0.x, w0.y, w0.z, w0.w, w1.x, w1.y, w1.z, w1.w};
#pragma unroll
    for (int i = 0; i < 4; ++i)
#pragma unroll
      for (int j = 0; j < 8; ++j) acc[i][j] = fmaf(av[i], wv[j], acc[i][j]);
  }
  if (TO_LDS) {
#pragma unroll
    for (int j = 0; j < 8; ++j) {
      float4 o;
      o.x = RELU ? fmaxf(acc[0][j], 0.f) : acc[0][j];
      o.y = RELU ? fmaxf(acc[1][j], 0.f) : acc[1][j];
      o.z = RELU ? fmaxf(acc[2][j], 0.f) : acc[2][j];
      o.w = RELU ? fmaxf(acc[3][j], 0.f) : acc[3][j];
      *(float4*)(&Hout[tx * 8 + j][ty * 4]) = o;
    }
  } else {
#pragma unroll
    for (int i = 0; i < 4; ++i)
#pragma unroll
      for (int j = 0; j < 8; ++j)
        accret[i][j] = RELU ? fmaxf(acc[i][j], 0.f) : acc[i][j];
  }
}

// Stage global [rows][FIN] row-major -> LDS transposed [k][e], zero-fill OOB.
template <int FIN>
__device__ __forceinline__ void stage_T(const float* __restrict__ g,
                                        float (*__restrict__ H)[LP], int r0,
                                        int nR, int tid) {
  constexpr int QV = 128 * FIN / 4;  // total float4s
#pragma unroll
  for (int q = tid; q < QV; q += 256) {
    int e = q / (FIN / 4), c = q % (FIN / 4);
    float4 v = make_float4(0.f, 0.f, 0.f, 0.f);
    if (r0 + e < nR) v = *(const float4*)(g + (size_t)(r0 + e) * FIN + c * 4);
    H[c * 4 + 0][e] = v.x;
    H[c * 4 + 1][e] = v.y;
    H[c * 4 + 2][e] = v.z;
    H[c * 4 + 3][e] = v.w;
  }
}

// ---------------------------------------------------------------------------
__global__ void degrees_k(const int* __restrict__ src, const int* __restrict__ dst,
                          float* __restrict__ degO, float* __restrict__ degI) {
  int e = blockIdx.x * 256 + threadIdx.x;
  if (e < NE0 + NE1) {
    atomicAdd(degO + src[e], 1.0f);
    atomicAdd(degI + dst[e], 1.0f);
  }
}

// ---------------------------------------------------------------------------
__global__ __launch_bounds__(256, 2) void node_mlp_k(
    const float* __restrict__ nf, const float* __restrict__ w0,
    const float* __restrict__ b0, const float* __restrict__ w1,
    const float* __restrict__ b1, const float* __restrict__ w2,
    const float* __restrict__ b2, float* __restrict__ hn) {
  __shared__ float Ha[64][LP];
  __shared__ float Hb[64][LP];
  int tid = threadIdx.x, tx = tid % 8, ty = tid / 8;
  int r0 = blockIdx.x * 128;
  stage_T<32>(nf, Ha, r0, N_NODES, tid);
  __syncthreads();
  layer_core<32, true, true>(Ha, Hb, w0, b0, tx, ty, nullptr);
  __syncthreads();
  layer_core<64, true, true>(Hb, Ha, w1, b1, tx, ty, nullptr);
  __syncthreads();
  float acc[4][8];
  layer_core<64, false, false>(Ha, nullptr, w2, b2, tx, ty, acc);
#pragma unroll
  for (int i = 0; i < 4; ++i) {
    int n = r0 + ty * 4 + i;
    if (n >= N_NODES) continue;
    *(float4*)(hn + (size_t)n * DD + tx * 8) =
        make_float4(acc[i][0], acc[i][1], acc[i][2], acc[i][3]);
    *(float4*)(hn + (size_t)n * DD + tx * 8 + 4) =
        make_float4(acc[i][4], acc[i][5], acc[i][6], acc[i][7]);
  }
}

// ---------------------------------------------------------------------------
// Fused: edge MLP (tiled GEMM, never hits HBM) + conv1 message + atomic scatter
// ---------------------------------------------------------------------------
template <int FIN>
__global__ __launch_bounds__(256, 2) void edge_conv1_k(
    const float* __restrict__ ef, const float* __restrict__ w0,
    const float* __restrict__ b0, const float* __restrict__ w1,
    const float* __restrict__ b1, const float* __restrict__ w2,
    const float* __restrict__ b2, const float* __restrict__ hn,
    const int* __restrict__ src, const int* __restrict__ dst,
    const float* __restrict__ degO, const float* __restrict__ degI,
    float* __restrict__ agg1, int nE, int ebase) {
  __shared__ float Ha[64][LP];
  __shared__ float Hb[64][LP];
  __shared__ float nrm[128];
  __shared__ int sA[128], dA[128];
  int tid = threadIdx.x, tx = tid % 8, ty = tid / 8;
  int e0 = blockIdx.x * 128;
  stage_T<FIN>(ef, Ha, e0, nE, tid);
  if (tid < 128) {
    int e = tid, ge = ebase + e0 + e;
    int s = 0, d = 0;
    float nm = 0.f;
    if (e0 + e < nE) {
      s = src[ge];
      d = dst[ge];
      nm = rsqrtf(fmaxf(degO[s], 1.f) * fmaxf(degI[d], 1.f));
    }
    sA[e] = s; dA[e] = d; nrm[e] = nm;
  }
  __syncthreads();
  layer_core<FIN, true, true>(Ha, Hb, w0, b0, tx, ty, nullptr);
  __syncthreads();
  layer_core<64, true, true>(Hb, Ha, w1, b1, tx, ty, nullptr);
  __syncthreads();
  float acc[4][8];
  layer_core<64, false, false>(Ha, nullptr, w2, b2, tx, ty, acc);  // he tile
#pragma unroll
  for (int i = 0; i < 4; ++i) {
    int e = ty * 4 + i;
    if (e0 + e >= nE) continue;
    int s = sA[e], d = dA[e];
    float nm = nrm[e];
    float4 hs0 = *(const float4*)(hn + (size_t)s * DD + tx * 8);
    float4 hs1 = *(const float4*)(hn + (size_t)s * DD + tx * 8 + 4);
    float4 hd0 = *(const float4*)(hn + (size_t)d * DD + tx * 8);
    float4 hd1 = *(const float4*)(hn + (size_t)d * DD + tx * 8 + 4);
    const float hv[8] = {hs0.x + hd0.x, hs0.y + hd0.y, hs0.z + hd0.z,
                         hs0.w + hd0.w, hs1.x + hd1.x, hs1.y + hd1.y,
                         hs1.z + hd1.z, hs1.w + hd1.w};
    float* ag = agg1 + (size_t)d * DD + tx * 8;
#pragma unroll
    for (int j = 0; j < 8; ++j) atomicAdd(ag + j, (acc[i][j] + hv[j]) * nm);
  }
}

// ---------------------------------------------------------------------------
// conv1 node side: h1 = relu(agg1 @ c1_w + c1_b); collapse through c2_w to a
// scalar (linearity of segment_sum) -> conv2 scatters scalars, 64x less.
// ---------------------------------------------------------------------------
__global__ __launch_bounds__(256, 2) void conv1_node_k(
    const float* __restrict__ agg1, const float* __restrict__ c1w,
    const float* __restrict__ c1b, const float* __restrict__ c2w,
    const float* __restrict__ c2b, float* __restrict__ sbuf,
    float* __restrict__ out) {
  __shared__ float Ha[64][LP];
  int tid = threadIdx.x, tx = tid % 8, ty = tid / 8;
  int r0 = blockIdx.x * 128;
  stage_T<64>(agg1, Ha, r0, N_NODES, tid);
  __syncthreads();
  float acc[4][8];
  layer_core<64, true, false>(Ha, nullptr, c1w, c1b, tx, ty, acc);
  float4 c0 = *(const float4*)(c2w + tx * 8);
  float4 c1 = *(const float4*)(c2w + tx * 8 + 4);
  const float cw[8] = {c0.x, c0.y, c0.z, c0.w, c1.x, c1.y, c1.z, c1.w};
  float cb = c2b[0];
#pragma unroll
  for (int i = 0; i < 4; ++i) {
    float s = 0.f;
#pragma unroll
    for (int j = 0; j < 8; ++j) s = fmaf(acc[i][j], cw[j], s);
    s += __shfl_xor(s, 1);
    s += __shfl_xor(s, 2);
    s += __shfl_xor(s, 4);
    int n = r0 + ty * 4 + i;
    if (tx == 0 && n < N_NODES) {
      sbuf[n] = s;
      out[n] = cb;
    }
  }
}

// ---------------------------------------------------------------------------
__global__ void conv2_edge_k(const float* __restrict__ sbuf,
                             const int* __restrict__ src,
                             const int* __restrict__ dst,
                             const float* __restrict__ degO,
                             const float* __restrict__ degI,
                             float* __restrict__ out) {
  int e = blockIdx.x * 256 + threadIdx.x;
  if (e < NE0 + NE1) {
    int s = src[e], d = dst[e];
    float norm = rsqrtf(fmaxf(degO[s], 1.f) * fmaxf(degI[d], 1.f));
    atomicAdd(out + d, norm * sbuf[s]);
  }
}

// ---------------------------------------------------------------------------
extern "C" void kernel_launch(void* const* d_in, const int* in_sizes, int n_in,
                              void* d_out, int out_size, void* d_ws,
                              size_t ws_size, hipStream_t stream) {
  const float* nf   = (const float*)d_in[0];
  const float* ef0  = (const float*)d_in[1];
  const float* ef1  = (const float*)d_in[2];
  const float* n_w0 = (const float*)d_in[3];  const float* n_b0 = (const float*)d_in[4];
  const float* n_w1 = (const float*)d_in[5];  const float* n_b1 = (const float*)d_in[6];
  const float* n_w2 = (const float*)d_in[7];  const float* n_b2 = (const float*)d_in[8];
  const float* e0w0 = (const float*)d_in[9];  const float* e0b0 = (const float*)d_in[10];
  const float* e0w1 = (const float*)d_in[11]; const float* e0b1 = (const float*)d_in[12];
  const float* e0w2 = (const float*)d_in[13]; const float* e0b2 = (const float*)d_in[14];
  const float* e1w0 = (const float*)d_in[15]; const float* e1b0 = (const float*)d_in[16];
  const float* e1w1 = (const float*)d_in[17]; const float* e1b1 = (const float*)d_in[18];
  const float* e1w2 = (const float*)d_in[19]; const float* e1b2 = (const float*)d_in[20];
  const float* c1w  = (const float*)d_in[21]; const float* c1b  = (const float*)d_in[22];
  const float* c2w  = (const float*)d_in[23]; const float* c2b  = (const float*)d_in[24];
  const int* src = (const int*)d_in[25];
  const int* dst = (const int*)d_in[26];
  float* out = (float*)d_out;

  // Workspace (floats): hn[3.2M] | agg1[3.2M] | degO[50K] | degI[50K] | sbuf[50K]
  float* ws   = (float*)d_ws;
  float* hn   = ws;
  float* agg1 = ws + 3200000;
  float* degO = ws + 6400000;
  float* degI = degO + N_NODES;
  float* sbuf = degI + N_NODES;

  hipMemsetAsync(agg1, 0, (size_t)(3200000 + 2 * N_NODES) * sizeof(float),
                 stream);

  degrees_k<<<(NE0 + NE1 + 255) / 256, 256, 0, stream>>>(src, dst, degO, degI);
  node_mlp_k<<<(N_NODES + 127) / 128, 256, 0, stream>>>(nf, n_w0, n_b0, n_w1,
                                                        n_b1, n_w2, n_b2, hn);
  edge_conv1_k<16><<<(NE0 + 127) / 128, 256, 0, stream>>>(
      ef0, e0w0, e0b0, e0w1, e0b1, e0w2, e0b2, hn, src, dst, degO, degI, agg1,
      NE0, 0);
  edge_conv1_k<8><<<(NE1 + 127) / 128, 256, 0, stream>>>(
      ef1, e1w0, e1b0, e1w1, e1b1, e1w2, e1b2, hn, src, dst, degO, degI, agg1,
      NE1, NE0);
  conv1_node_k<<<(N_NODES + 127) / 128, 256, 0, stream>>>(agg1, c1w, c1b, c2w,
                                                          c2b, sbuf, out);
  conv2_edge_k<<<(NE0 + NE1 + 255) / 256, 256, 0, stream>>>(sbuf, src, dst,
                                                            degO, degI, out);
}

// Round 3
// 552.004 us; speedup vs baseline: 26.0902x; 3.0734x over previous
//
#include <hip/hip_runtime.h>

#define N_NODES 50000
#define NE0 500000
#define NE1 300000
#define NE (NE0 + NE1)
#define DD 64
#define LP 132  // LDS row stride (floats): +4 skew kills transposed-write conflicts

// ---------------------------------------------------------------------------
// Tiled dense layer (unchanged from round 2). Input Hin[k][e] transposed in
// LDS. Thread (tx,ty): rows e=ty*4.., cols f=tx*8.. ; 32 FMA per k-step.
// ---------------------------------------------------------------------------
template <int K, bool RELU, bool TO_LDS>
__device__ __forceinline__ void layer_core(
    const float (*__restrict__ Hin)[LP], float (*__restrict__ Hout)[LP],
    const float* __restrict__ W, const float* __restrict__ B,
    int tx, int ty, float (*__restrict__ accret)[8]) {
  float acc[4][8];
  float4 bv0 = *(const float4*)(B + tx * 8);
  float4 bv1 = *(const float4*)(B + tx * 8 + 4);
  const float bb[8] = {bv0.x, bv0.y, bv0.z, bv0.w, bv1.x, bv1.y, bv1.z, bv1.w};
#pragma unroll
  for (int i = 0; i < 4; ++i)
#pragma unroll
    for (int j = 0; j < 8; ++j) acc[i][j] = bb[j];
#pragma unroll 8
  for (int k = 0; k < K; ++k) {
    float4 a = *(const float4*)(&Hin[k][ty * 4]);
    float4 w0 = *(const float4*)(W + k * 64 + tx * 8);
    float4 w1 = *(const float4*)(W + k * 64 + tx * 8 + 4);
    const float av[4] = {a.x, a.y, a.z, a.w};
    const float wv[8] = {w0.x, w0.y, w0.z, w0.w, w1.x, w1.y, w1.z, w1.w};
#pragma unroll
    for (int i = 0; i < 4; ++i)
#pragma unroll
      for (int j = 0; j < 8; ++j) acc[i][j] = fmaf(av[i], wv[j], acc[i][j]);
  }
  if (TO_LDS) {
#pragma unroll
    for (int j = 0; j < 8; ++j) {
      float4 o;
      o.x = RELU ? fmaxf(acc[0][j], 0.f) : acc[0][j];
      o.y = RELU ? fmaxf(acc[1][j], 0.f) : acc[1][j];
      o.z = RELU ? fmaxf(acc[2][j], 0.f) : acc[2][j];
      o.w = RELU ? fmaxf(acc[3][j], 0.f) : acc[3][j];
      *(float4*)(&Hout[tx * 8 + j][ty * 4]) = o;
    }
  } else {
#pragma unroll
    for (int i = 0; i < 4; ++i)
#pragma unroll
      for (int j = 0; j < 8; ++j)
        accret[i][j] = RELU ? fmaxf(acc[i][j], 0.f) : acc[i][j];
  }
}

template <int FIN>
__device__ __forceinline__ void stage_T(const float* __restrict__ g,
                                        float (*__restrict__ H)[LP], int r0,
                                        int nR, int tid) {
  constexpr int QV = 128 * FIN / 4;
#pragma unroll
  for (int q = tid; q < QV; q += 256) {
    int e = q / (FIN / 4), c = q % (FIN / 4);
    float4 v = make_float4(0.f, 0.f, 0.f, 0.f);
    if (r0 + e < nR) v = *(const float4*)(g + (size_t)(r0 + e) * FIN + c * 4);
    H[c * 4 + 0][e] = v.x;
    H[c * 4 + 1][e] = v.y;
    H[c * 4 + 2][e] = v.z;
    H[c * 4 + 3][e] = v.w;
  }
}

// ============================ shared kernels ===============================
__global__ __launch_bounds__(256, 2) void node_mlp_k(
    const float* __restrict__ nf, const float* __restrict__ w0,
    const float* __restrict__ b0, const float* __restrict__ w1,
    const float* __restrict__ b1, const float* __restrict__ w2,
    const float* __restrict__ b2, float* __restrict__ hn) {
  __shared__ float Ha[64][LP];
  __shared__ float Hb[64][LP];
  int tid = threadIdx.x, tx = tid % 8, ty = tid / 8;
  int r0 = blockIdx.x * 128;
  stage_T<32>(nf, Ha, r0, N_NODES, tid);
  __syncthreads();
  layer_core<32, true, true>(Ha, Hb, w0, b0, tx, ty, nullptr);
  __syncthreads();
  layer_core<64, true, true>(Hb, Ha, w1, b1, tx, ty, nullptr);
  __syncthreads();
  float acc[4][8];
  layer_core<64, false, false>(Ha, nullptr, w2, b2, tx, ty, acc);
#pragma unroll
  for (int i = 0; i < 4; ++i) {
    int n = r0 + ty * 4 + i;
    if (n >= N_NODES) continue;
    *(float4*)(hn + (size_t)n * DD + tx * 8) =
        make_float4(acc[i][0], acc[i][1], acc[i][2], acc[i][3]);
    *(float4*)(hn + (size_t)n * DD + tx * 8 + 4) =
        make_float4(acc[i][4], acc[i][5], acc[i][6], acc[i][7]);
  }
}

// ========================= GATHER (no-fp-atomic) path ======================
__global__ void count_k(const int* __restrict__ src, const int* __restrict__ dst,
                        int* __restrict__ cntO, int* __restrict__ cntI) {
  int e = blockIdx.x * 256 + threadIdx.x;
  if (e < NE) {
    atomicAdd(cntO + src[e], 1);
    atomicAdd(cntI + dst[e], 1);
  }
}

__device__ __forceinline__ int block_scan_excl(int x, int tid, int* total) {
  int lane = tid & 63, w = tid >> 6;
  int incl = x;
#pragma unroll
  for (int d = 1; d < 64; d <<= 1) {
    int y = __shfl_up(incl, d);
    if (lane >= d) incl += y;
  }
  __shared__ int wsum[4];
  if (lane == 63) wsum[w] = incl;
  __syncthreads();
  int woff = 0;
  if (w > 0) woff = wsum[0];
  if (w > 1) woff += wsum[1];
  if (w > 2) woff += wsum[2];
  *total = wsum[0] + wsum[1] + wsum[2] + wsum[3];
  return woff + incl - x;
}

__global__ __launch_bounds__(256) void scan1_k(const int* __restrict__ cnt,
                                               int* __restrict__ rowptr,
                                               int* __restrict__ bsum) {
  int i = blockIdx.x * 256 + threadIdx.x;
  int x = (i < N_NODES) ? cnt[i] : 0;
  int tot;
  int ex = block_scan_excl(x, threadIdx.x, &tot);
  if (i < N_NODES) rowptr[i] = ex;
  if (threadIdx.x == 0) bsum[blockIdx.x] = tot;
}

__global__ __launch_bounds__(256) void scan2_k(const int* __restrict__ bsum,
                                               int* __restrict__ boff,
                                               int* __restrict__ rowptr, int nb) {
  int i = threadIdx.x;
  int x = (i < nb) ? bsum[i] : 0;
  int tot;
  int ex = block_scan_excl(x, i, &tot);
  if (i < nb) boff[i] = ex;
  if (i == 0) rowptr[N_NODES] = tot;
}

__global__ void scan3_k(int* __restrict__ rowptr, const int* __restrict__ boff) {
  int i = blockIdx.x * 256 + threadIdx.x;
  if (i < N_NODES && blockIdx.x > 0) rowptr[i] += boff[blockIdx.x];
}

__global__ void scatter_k(const int* __restrict__ src, const int* __restrict__ dst,
                          const int* __restrict__ rowptr, int* __restrict__ fill,
                          const int* __restrict__ cntO, const int* __restrict__ cntI,
                          int* __restrict__ ceid, int* __restrict__ csrc,
                          float* __restrict__ cnrm) {
  int e = blockIdx.x * 256 + threadIdx.x;
  if (e < NE) {
    int s = src[e], d = dst[e];
    int slot = rowptr[d] + atomicAdd(fill + d, 1);
    ceid[slot] = e;
    csrc[slot] = s;
    cnrm[slot] = rsqrtf((float)max(cntO[s], 1) * (float)max(cntI[d], 1));
  }
}

// Edge MLP as pure tiled GEMM -> he (no scatter, no atomics).
template <int FIN>
__global__ __launch_bounds__(256, 2) void edge_mlp_k(
    const float* __restrict__ ef, const float* __restrict__ w0,
    const float* __restrict__ b0, const float* __restrict__ w1,
    const float* __restrict__ b1, const float* __restrict__ w2,
    const float* __restrict__ b2, float* __restrict__ he, int nE) {
  __shared__ float Ha[64][LP];
  __shared__ float Hb[64][LP];
  int tid = threadIdx.x, tx = tid % 8, ty = tid / 8;
  int r0 = blockIdx.x * 128;
  stage_T<FIN>(ef, Ha, r0, nE, tid);
  __syncthreads();
  layer_core<FIN, true, true>(Ha, Hb, w0, b0, tx, ty, nullptr);
  __syncthreads();
  layer_core<64, true, true>(Hb, Ha, w1, b1, tx, ty, nullptr);
  __syncthreads();
  float acc[4][8];
  layer_core<64, false, false>(Ha, nullptr, w2, b2, tx, ty, acc);
#pragma unroll
  for (int i = 0; i < 4; ++i) {
    int e = r0 + ty * 4 + i;
    if (e >= nE) continue;
    *(float4*)(he + (size_t)e * DD + tx * 8) =
        make_float4(acc[i][0], acc[i][1], acc[i][2], acc[i][3]);
    *(float4*)(he + (size_t)e * DD + tx * 8 + 4) =
        make_float4(acc[i][4], acc[i][5], acc[i][6], acc[i][7]);
  }
}

// Wave-per-node gather + fused c1 GEMM + c2 collapse. Zero atomics.
// agg1[d] = sum_j nm*(he[eid]+hn[src]) + (sum nm)*hn[d]; sbuf[d]=relu(agg@c1w+b)@c2w
__global__ __launch_bounds__(256) void gather_conv1_k(
    const int* __restrict__ rowptr, const int* __restrict__ ceid,
    const int* __restrict__ csrc, const float* __restrict__ cnrm,
    const float* __restrict__ he, const float* __restrict__ hn,
    const float* __restrict__ c1w, const float* __restrict__ c1b,
    const float* __restrict__ c2w, float* __restrict__ sbuf) {
  int w = threadIdx.x >> 6, lane = threadIdx.x & 63;
  int n = blockIdx.x * 4 + w;
  if (n >= N_NODES) return;
  int r0 = rowptr[n], r1 = rowptr[n + 1];
  float acc = 0.f, sn = 0.f;
  for (int j = r0; j < r1; ++j) {
    int eid = ceid[j], s = csrc[j];
    float nm = cnrm[j];
    acc = fmaf(nm, he[(size_t)eid * DD + lane] + hn[(size_t)s * DD + lane], acc);
    sn += nm;
  }
  acc = fmaf(sn, hn[(size_t)n * DD + lane], acc);
  __shared__ float A[4][64];
  A[w][lane] = acc;  // wave-local LDS RAW (no cross-wave sharing -> no barrier)
  float h = c1b[lane];
#pragma unroll 8
  for (int k = 0; k < 64; ++k) h = fmaf(A[w][k], c1w[k * DD + lane], h);
  h = fmaxf(h, 0.f);
  float v = h * c2w[lane];
#pragma unroll
  for (int d = 32; d; d >>= 1) v += __shfl_xor(v, d);
  if (lane == 0) sbuf[n] = v;
}

// conv2: thread-per-node scalar gather. out overwritten -> no seed, no atomics.
__global__ void conv2_gather_k(const int* __restrict__ rowptr,
                               const int* __restrict__ csrc,
                               const float* __restrict__ cnrm,
                               const float* __restrict__ sbuf,
                               const float* __restrict__ c2b,
                               float* __restrict__ out) {
  int n = blockIdx.x * 256 + threadIdx.x;
  if (n < N_NODES) {
    int r0 = rowptr[n], r1 = rowptr[n + 1];
    float a = 0.f;
    for (int j = r0; j < r1; ++j) a = fmaf(cnrm[j], sbuf[csrc[j]], a);
    out[n] = a + c2b[0];
  }
}

// ===================== FALLBACK (round-2 atomic) path ======================
__global__ void degrees_k(const int* __restrict__ src, const int* __restrict__ dst,
                          float* __restrict__ degO, float* __restrict__ degI) {
  int e = blockIdx.x * 256 + threadIdx.x;
  if (e < NE) {
    atomicAdd(degO + src[e], 1.0f);
    atomicAdd(degI + dst[e], 1.0f);
  }
}

template <int FIN>
__global__ __launch_bounds__(256, 2) void edge_conv1_k(
    const float* __restrict__ ef, const float* __restrict__ w0,
    const float* __restrict__ b0, const float* __restrict__ w1,
    const float* __restrict__ b1, const float* __restrict__ w2,
    const float* __restrict__ b2, const float* __restrict__ hn,
    const int* __restrict__ src, const int* __restrict__ dst,
    const float* __restrict__ degO, const float* __restrict__ degI,
    float* __restrict__ agg1, int nE, int ebase) {
  __shared__ float Ha[64][LP];
  __shared__ float Hb[64][LP];
  __shared__ float nrm[128];
  __shared__ int sA[128], dA[128];
  int tid = threadIdx.x, tx = tid % 8, ty = tid / 8;
  int e0 = blockIdx.x * 128;
  stage_T<FIN>(ef, Ha, e0, nE, tid);
  if (tid < 128) {
    int e = tid, ge = ebase + e0 + e;
    int s = 0, d = 0;
    float nm = 0.f;
    if (e0 + e < nE) {
      s = src[ge];
      d = dst[ge];
      nm = rsqrtf(fmaxf(degO[s], 1.f) * fmaxf(degI[d], 1.f));
    }
    sA[e] = s; dA[e] = d; nrm[e] = nm;
  }
  __syncthreads();
  layer_core<FIN, true, true>(Ha, Hb, w0, b0, tx, ty, nullptr);
  __syncthreads();
  layer_core<64, true, true>(Hb, Ha, w1, b1, tx, ty, nullptr);
  __syncthreads();
  float acc[4][8];
  layer_core<64, false, false>(Ha, nullptr, w2, b2, tx, ty, acc);
#pragma unroll
  for (int i = 0; i < 4; ++i) {
    int e = ty * 4 + i;
    if (e0 + e >= nE) continue;
    int s = sA[e], d = dA[e];
    float nm = nrm[e];
    float4 hs0 = *(const float4*)(hn + (size_t)s * DD + tx * 8);
    float4 hs1 = *(const float4*)(hn + (size_t)s * DD + tx * 8 + 4);
    float4 hd0 = *(const float4*)(hn + (size_t)d * DD + tx * 8);
    float4 hd1 = *(const float4*)(hn + (size_t)d * DD + tx * 8 + 4);
    const float hv[8] = {hs0.x + hd0.x, hs0.y + hd0.y, hs0.z + hd0.z,
                         hs0.w + hd0.w, hs1.x + hd1.x, hs1.y + hd1.y,
                         hs1.z + hd1.z, hs1.w + hd1.w};
    float* ag = agg1 + (size_t)d * DD + tx * 8;
#pragma unroll
    for (int j = 0; j < 8; ++j) atomicAdd(ag + j, (acc[i][j] + hv[j]) * nm);
  }
}

__global__ __launch_bounds__(256, 2) void conv1_node_k(
    const float* __restrict__ agg1, const float* __restrict__ c1w,
    const float* __restrict__ c1b, const float* __restrict__ c2w,
    const float* __restrict__ c2b, float* __restrict__ sbuf,
    float* __restrict__ out) {
  __shared__ float Ha[64][LP];
  int tid = threadIdx.x, tx = tid % 8, ty = tid / 8;
  int r0 = blockIdx.x * 128;
  stage_T<64>(agg1, Ha, r0, N_NODES, tid);
  __syncthreads();
  float acc[4][8];
  layer_core<64, true, false>(Ha, nullptr, c1w, c1b, tx, ty, acc);
  float4 c0 = *(const float4*)(c2w + tx * 8);
  float4 c1 = *(const float4*)(c2w + tx * 8 + 4);
  const float cw[8] = {c0.x, c0.y, c0.z, c0.w, c1.x, c1.y, c1.z, c1.w};
  float cb = c2b[0];
#pragma unroll
  for (int i = 0; i < 4; ++i) {
    float s = 0.f;
#pragma unroll
    for (int j = 0; j < 8; ++j) s = fmaf(acc[i][j], cw[j], s);
    s += __shfl_xor(s, 1);
    s += __shfl_xor(s, 2);
    s += __shfl_xor(s, 4);
    int n = r0 + ty * 4 + i;
    if (tx == 0 && n < N_NODES) {
      sbuf[n] = s;
      out[n] = cb;
    }
  }
}

__global__ void conv2_edge_k(const float* __restrict__ sbuf,
                             const int* __restrict__ src,
                             const int* __restrict__ dst,
                             const float* __restrict__ degO,
                             const float* __restrict__ degI,
                             float* __restrict__ out) {
  int e = blockIdx.x * 256 + threadIdx.x;
  if (e < NE) {
    int s = src[e], d = dst[e];
    float norm = rsqrtf(fmaxf(degO[s], 1.f) * fmaxf(degI[d], 1.f));
    atomicAdd(out + d, norm * sbuf[s]);
  }
}

// ---------------------------------------------------------------------------
extern "C" void kernel_launch(void* const* d_in, const int* in_sizes, int n_in,
                              void* d_out, int out_size, void* d_ws,
                              size_t ws_size, hipStream_t stream) {
  const float* nf   = (const float*)d_in[0];
  const float* ef0  = (const float*)d_in[1];
  const float* ef1  = (const float*)d_in[2];
  const float* n_w0 = (const float*)d_in[3];  const float* n_b0 = (const float*)d_in[4];
  const float* n_w1 = (const float*)d_in[5];  const float* n_b1 = (const float*)d_in[6];
  const float* n_w2 = (const float*)d_in[7];  const float* n_b2 = (const float*)d_in[8];
  const float* e0w0 = (const float*)d_in[9];  const float* e0b0 = (const float*)d_in[10];
  const float* e0w1 = (const float*)d_in[11]; const float* e0b1 = (const float*)d_in[12];
  const float* e0w2 = (const float*)d_in[13]; const float* e0b2 = (const float*)d_in[14];
  const float* e1w0 = (const float*)d_in[15]; const float* e1b0 = (const float*)d_in[16];
  const float* e1w1 = (const float*)d_in[17]; const float* e1b1 = (const float*)d_in[18];
  const float* e1w2 = (const float*)d_in[19]; const float* e1b2 = (const float*)d_in[20];
  const float* c1w  = (const float*)d_in[21]; const float* c1b  = (const float*)d_in[22];
  const float* c2w  = (const float*)d_in[23]; const float* c2b  = (const float*)d_in[24];
  const int* src = (const int*)d_in[25];
  const int* dst = (const int*)d_in[26];
  float* out = (float*)d_out;
  float* ws = (float*)d_ws;

  // ---- gather-path workspace layout (floats/ints, 4B units) ----
  float* hn     = ws;                       // 3,200,000
  float* sbuf   = ws + 3200000;             // 50,000
  int*   rowptr = (int*)(ws + 3250000);     // 50,001
  int*   cntI   = (int*)(ws + 3300008);     // 50,000 (cntI,cntO,fill contiguous)
  int*   cntO   = (int*)(ws + 3350008);     // 50,000
  int*   fill   = (int*)(ws + 3400008);     // 50,000
  int*   bsum   = (int*)(ws + 3450008);     // 256
  int*   boff   = (int*)(ws + 3450264);     // 256
  int*   ceid   = (int*)(ws + 3460000);     // 800,000
  int*   csrc   = (int*)(ws + 4260000);     // 800,000
  float* cnrm   = ws + 5060000;             // 800,000
  float* he     = ws + 5860000;             // 51,200,000 -> end 57,060,000
  const size_t NEED = 57060000ull * 4ull;

  const int NB = (N_NODES + 255) / 256;  // 196

  if (ws_size >= NEED) {
    // ===== gather path: zero fp atomics =====
    hipMemsetAsync(cntI, 0, (size_t)3 * N_NODES * sizeof(int), stream);
    count_k<<<(NE + 255) / 256, 256, 0, stream>>>(src, dst, cntO, cntI);
    scan1_k<<<NB, 256, 0, stream>>>(cntI, rowptr, bsum);
    scan2_k<<<1, 256, 0, stream>>>(bsum, boff, rowptr, NB);
    scan3_k<<<NB, 256, 0, stream>>>(rowptr, boff);
    scatter_k<<<(NE + 255) / 256, 256, 0, stream>>>(src, dst, rowptr, fill,
                                                    cntO, cntI, ceid, csrc, cnrm);
    node_mlp_k<<<(N_NODES + 127) / 128, 256, 0, stream>>>(
        nf, n_w0, n_b0, n_w1, n_b1, n_w2, n_b2, hn);
    edge_mlp_k<16><<<(NE0 + 127) / 128, 256, 0, stream>>>(
        ef0, e0w0, e0b0, e0w1, e0b1, e0w2, e0b2, he, NE0);
    edge_mlp_k<8><<<(NE1 + 127) / 128, 256, 0, stream>>>(
        ef1, e1w0, e1b0, e1w1, e1b1, e1w2, e1b2, he + (size_t)NE0 * DD, NE1);
    gather_conv1_k<<<(N_NODES + 3) / 4, 256, 0, stream>>>(
        rowptr, ceid, csrc, cnrm, he, hn, c1w, c1b, c2w, sbuf);
    conv2_gather_k<<<NB, 256, 0, stream>>>(rowptr, csrc, cnrm, sbuf, c2b, out);
  } else {
    // ===== fallback: round-2 atomic path =====
    float* agg1 = ws + 3200000;
    float* degO = ws + 6400000;
    float* degI = degO + N_NODES;
    float* sbufF = degI + N_NODES;
    hipMemsetAsync(agg1, 0, (size_t)(3200000 + 2 * N_NODES) * sizeof(float),
                   stream);
    degrees_k<<<(NE + 255) / 256, 256, 0, stream>>>(src, dst, degO, degI);
    node_mlp_k<<<(N_NODES + 127) / 128, 256, 0, stream>>>(
        nf, n_w0, n_b0, n_w1, n_b1, n_w2, n_b2, hn);
    edge_conv1_k<16><<<(NE0 + 127) / 128, 256, 0, stream>>>(
        ef0, e0w0, e0b0, e0w1, e0b1, e0w2, e0b2, hn, src, dst, degO, degI,
        agg1, NE0, 0);
    edge_conv1_k<8><<<(NE1 + 127) / 128, 256, 0, stream>>>(
        ef1, e1w0, e1b0, e1w1, e1b1, e1w2, e1b2, hn, src, dst, degO, degI,
        agg1, NE1, NE0);
    conv1_node_k<<<(N_NODES + 127) / 128, 256, 0, stream>>>(
        agg1, c1w, c1b, c2w, c2b, sbufF, out);
    conv2_edge_k<<<(NE + 255) / 256, 256, 0, stream>>>(sbufF, src, dst, degO,
                                                       degI, out);
  }
}

// Round 4
// 518.267 us; speedup vs baseline: 27.7885x; 1.0651x over previous
//
#include <hip/hip_runtime.h>

#define N_NODES 50000
#define NE0 500000
#define NE1 300000
#define NE (NE0 + NE1)
#define DD 64
#define AS 68  // activation LDS row stride (floats): 68*4=272B, 16B-aligned, 17 mod 8 = 1 -> minimal b128 serialization

// ---------------------------------------------------------------------------
// Wave-structured dense layer. lane = row (64 rows/block), wave owns cols
// [wq, wq+16). Activations Hin[row][k] contiguous per lane -> ds_read_b128
// per 4 k. Weights at W[k*64+wq..] are WAVE-UNIFORM (wq readfirstlane'd) ->
// compiler emits scalar s_load (SMEM path), freeing vector-memory entirely.
// 64 FMA per 1 ds_read_b128. acc[16] per lane.
// ---------------------------------------------------------------------------
template <int K, bool RELU>
__device__ __forceinline__ void wlayer(const float (*__restrict__ Hin)[AS],
                                       float (*__restrict__ Hout)[AS],
                                       const float* __restrict__ W,
                                       const float* __restrict__ B, int lane,
                                       int wq, float* __restrict__ accout) {
  float acc[16];
  {
    const float4* bp = (const float4*)(B + wq);
    float4 b0 = bp[0], b1 = bp[1], b2 = bp[2], b3 = bp[3];
    acc[0] = b0.x; acc[1] = b0.y; acc[2] = b0.z; acc[3] = b0.w;
    acc[4] = b1.x; acc[5] = b1.y; acc[6] = b1.z; acc[7] = b1.w;
    acc[8] = b2.x; acc[9] = b2.y; acc[10] = b2.z; acc[11] = b2.w;
    acc[12] = b3.x; acc[13] = b3.y; acc[14] = b3.z; acc[15] = b3.w;
  }
#pragma unroll 4
  for (int k4 = 0; k4 < K; k4 += 4) {
    float4 a4 = *(const float4*)(&Hin[lane][k4]);
    const float av[4] = {a4.x, a4.y, a4.z, a4.w};
#pragma unroll
    for (int kk = 0; kk < 4; ++kk) {
      const float4* wp = (const float4*)(W + (k4 + kk) * DD + wq);
      float4 w0 = wp[0], w1 = wp[1], w2 = wp[2], w3 = wp[3];
      const float wv[16] = {w0.x, w0.y, w0.z, w0.w, w1.x, w1.y, w1.z, w1.w,
                            w2.x, w2.y, w2.z, w2.w, w3.x, w3.y, w3.z, w3.w};
#pragma unroll
      for (int j = 0; j < 16; ++j) acc[j] = fmaf(av[kk], wv[j], acc[j]);
    }
  }
  if (Hout) {
#pragma unroll
    for (int j = 0; j < 4; ++j) {
      float4 o;
      o.x = RELU ? fmaxf(acc[j * 4 + 0], 0.f) : acc[j * 4 + 0];
      o.y = RELU ? fmaxf(acc[j * 4 + 1], 0.f) : acc[j * 4 + 1];
      o.z = RELU ? fmaxf(acc[j * 4 + 2], 0.f) : acc[j * 4 + 2];
      o.w = RELU ? fmaxf(acc[j * 4 + 3], 0.f) : acc[j * 4 + 3];
      *(float4*)(&Hout[lane][wq + j * 4]) = o;
    }
  } else {
#pragma unroll
    for (int j = 0; j < 16; ++j)
      accout[j] = RELU ? fmaxf(acc[j], 0.f) : acc[j];
  }
}

// Stage global [rows][FIN] -> LDS Act[row][k] (row-major, NOT transposed).
template <int FIN>
__device__ __forceinline__ void stage_rows(const float* __restrict__ g,
                                           float (*__restrict__ H)[AS], int r0,
                                           int nR, int tid) {
  constexpr int Q = 64 * FIN / 4;
#pragma unroll
  for (int q = tid; q < Q; q += 256) {
    int r = q / (FIN / 4), c = q % (FIN / 4);
    float4 v = make_float4(0.f, 0.f, 0.f, 0.f);
    if (r0 + r < nR) v = *(const float4*)(g + (size_t)(r0 + r) * FIN + c * 4);
    *(float4*)(&H[r][c * 4]) = v;
  }
}

// ============================ CSR build ====================================
__global__ void count_k(const int* __restrict__ src, const int* __restrict__ dst,
                        int* __restrict__ cntO, int* __restrict__ cntI) {
  int e = blockIdx.x * 256 + threadIdx.x;
  if (e < NE) {
    atomicAdd(cntO + src[e], 1);
    atomicAdd(cntI + dst[e], 1);
  }
}

__device__ __forceinline__ int block_scan_excl(int x, int tid, int* total) {
  int lane = tid & 63, w = tid >> 6;
  int incl = x;
#pragma unroll
  for (int d = 1; d < 64; d <<= 1) {
    int y = __shfl_up(incl, d);
    if (lane >= d) incl += y;
  }
  __shared__ int wsum[4];
  if (lane == 63) wsum[w] = incl;
  __syncthreads();
  int woff = 0;
  if (w > 0) woff = wsum[0];
  if (w > 1) woff += wsum[1];
  if (w > 2) woff += wsum[2];
  *total = wsum[0] + wsum[1] + wsum[2] + wsum[3];
  return woff + incl - x;
}

__global__ __launch_bounds__(256) void scan1_k(const int* __restrict__ cnt,
                                               int* __restrict__ rowptr,
                                               int* __restrict__ bsum) {
  int i = blockIdx.x * 256 + threadIdx.x;
  int x = (i < N_NODES) ? cnt[i] : 0;
  int tot;
  int ex = block_scan_excl(x, threadIdx.x, &tot);
  if (i < N_NODES) rowptr[i] = ex;
  if (threadIdx.x == 0) bsum[blockIdx.x] = tot;
}

__global__ __launch_bounds__(256) void scan2_k(const int* __restrict__ bsum,
                                               int* __restrict__ boff,
                                               int* __restrict__ rowptr, int nb) {
  int i = threadIdx.x;
  int x = (i < nb) ? bsum[i] : 0;
  int tot;
  int ex = block_scan_excl(x, i, &tot);
  if (i < nb) boff[i] = ex;
  if (i == 0) rowptr[N_NODES] = tot;
}

__global__ void scan3_k(int* __restrict__ rowptr, const int* __restrict__ boff) {
  int i = blockIdx.x * 256 + threadIdx.x;
  if (i < N_NODES && blockIdx.x > 0) rowptr[i] += boff[blockIdx.x];
}

__global__ void scatter_k(const int* __restrict__ src, const int* __restrict__ dst,
                          const int* __restrict__ rowptr, int* __restrict__ fill,
                          const int* __restrict__ cntO, const int* __restrict__ cntI,
                          int* __restrict__ eslot, int* __restrict__ csrc,
                          float* __restrict__ cnrm) {
  int e = blockIdx.x * 256 + threadIdx.x;
  if (e < NE) {
    int s = src[e], d = dst[e];
    int slot = rowptr[d] + atomicAdd(fill + d, 1);
    eslot[e] = slot;
    csrc[slot] = s;
    cnrm[slot] = rsqrtf((float)max(cntO[s], 1) * (float)max(cntI[d], 1));
  }
}

// ============================ MLP kernels ==================================
__global__ __launch_bounds__(256, 4) void node_mlp_k(
    const float* __restrict__ nf, const float* __restrict__ w0,
    const float* __restrict__ b0, const float* __restrict__ w1,
    const float* __restrict__ b1, const float* __restrict__ w2,
    const float* __restrict__ b2, float* __restrict__ hn) {
  __shared__ float Ha[64][AS];
  __shared__ float Hb[64][AS];
  int tid = threadIdx.x, lane = tid & 63;
  int wq = __builtin_amdgcn_readfirstlane(tid >> 6) * 16;
  int r0 = blockIdx.x * 64;
  stage_rows<32>(nf, Ha, r0, N_NODES, tid);
  __syncthreads();
  wlayer<32, true>(Ha, Hb, w0, b0, lane, wq, nullptr);
  __syncthreads();
  wlayer<64, true>(Hb, Ha, w1, b1, lane, wq, nullptr);
  __syncthreads();
  float acc[16];
  wlayer<64, false>(Ha, nullptr, w2, b2, lane, wq, acc);
  int n = r0 + lane;
  if (n < N_NODES) {
    float* hp = hn + (size_t)n * DD + wq;
#pragma unroll
    for (int j = 0; j < 4; ++j)
      *(float4*)(hp + j * 4) = make_float4(acc[j * 4], acc[j * 4 + 1],
                                           acc[j * 4 + 2], acc[j * 4 + 3]);
  }
}

// Fused: edge MLP + u_add_v message + norm, written DIRECTLY to CSR slot
// order (msg[slot] = nm*(he + hn[src])). Random hn gather + scattered write
// hide under the FMA-dominant MLP; downstream gather becomes sequential.
template <int FIN>
__global__ __launch_bounds__(256, 4) void edge_mlp_k(
    const float* __restrict__ ef, const float* __restrict__ w0,
    const float* __restrict__ b0, const float* __restrict__ w1,
    const float* __restrict__ b1, const float* __restrict__ w2,
    const float* __restrict__ b2, const float* __restrict__ hn,
    const int* __restrict__ src, const int* __restrict__ dst,
    const int* __restrict__ cntO, const int* __restrict__ cntI,
    const int* __restrict__ eslot, float* __restrict__ msg, int nE, int ebase) {
  __shared__ float Ha[64][AS];
  __shared__ float Hb[64][AS];
  int tid = threadIdx.x, lane = tid & 63;
  int wq = __builtin_amdgcn_readfirstlane(tid >> 6) * 16;
  int e0 = blockIdx.x * 64;
  stage_rows<FIN>(ef, Ha, e0, nE, tid);
  __syncthreads();
  wlayer<FIN, true>(Ha, Hb, w0, b0, lane, wq, nullptr);
  __syncthreads();
  wlayer<64, true>(Hb, Ha, w1, b1, lane, wq, nullptr);
  __syncthreads();
  float acc[16];
  wlayer<64, false>(Ha, nullptr, w2, b2, lane, wq, acc);  // he chunk
  int e = e0 + lane;
  if (e < nE) {
    int ge = ebase + e;
    int slot = eslot[ge];
    int s = src[ge], d = dst[ge];
    float nm = rsqrtf((float)max(cntO[s], 1) * (float)max(cntI[d], 1));
    const float* hs = hn + (size_t)s * DD + wq;
    float* mp = msg + (size_t)slot * DD + wq;
#pragma unroll
    for (int j = 0; j < 4; ++j) {
      float4 h4 = *(const float4*)(hs + j * 4);
      float4 o;
      o.x = (acc[j * 4 + 0] + h4.x) * nm;
      o.y = (acc[j * 4 + 1] + h4.y) * nm;
      o.z = (acc[j * 4 + 2] + h4.z) * nm;
      o.w = (acc[j * 4 + 3] + h4.w) * nm;
      *(float4*)(mp + j * 4) = o;
    }
  }
}

// ======================= streaming gather + conv1 ==========================
// agg1[n] = sum_slots msg + (sum_slots cnrm)*hn[n]; then relu(agg@c1w+c1b)@c2w
__global__ __launch_bounds__(256) void gather_conv1_k(
    const int* __restrict__ rowptr, const float* __restrict__ cnrm,
    const float* __restrict__ msg, const float* __restrict__ hn,
    const float* __restrict__ c1w, const float* __restrict__ c1b,
    const float* __restrict__ c2w, float* __restrict__ sbuf) {
  int w = threadIdx.x >> 6, lane = threadIdx.x & 63;
  int n = blockIdx.x * 4 + w;
  if (n >= N_NODES) return;
  int r0 = rowptr[n], r1 = rowptr[n + 1];
  float acc = 0.f, sn = 0.f;
  for (int j = r0; j < r1; ++j) {
    acc += msg[(size_t)j * DD + lane];  // sequential 256B rows
    sn += cnrm[j];                      // uniform broadcast
  }
  acc = fmaf(sn, hn[(size_t)n * DD + lane], acc);
  __shared__ float A[4][64];
  A[w][lane] = acc;  // wave-local RAW, no barrier needed
  float h = c1b[lane];
#pragma unroll 8
  for (int k = 0; k < 64; ++k) h = fmaf(A[w][k], c1w[k * DD + lane], h);
  h = fmaxf(h, 0.f);
  float v = h * c2w[lane];
#pragma unroll
  for (int d = 32; d; d >>= 1) v += __shfl_xor(v, d);
  if (lane == 0) sbuf[n] = v;
}

__global__ void conv2_gather_k(const int* __restrict__ rowptr,
                               const int* __restrict__ csrc,
                               const float* __restrict__ cnrm,
                               const float* __restrict__ sbuf,
                               const float* __restrict__ c2b,
                               float* __restrict__ out) {
  int n = blockIdx.x * 256 + threadIdx.x;
  if (n < N_NODES) {
    int r0 = rowptr[n], r1 = rowptr[n + 1];
    float a = 0.f;
    for (int j = r0; j < r1; ++j) a = fmaf(cnrm[j], sbuf[csrc[j]], a);
    out[n] = a + c2b[0];
  }
}

// ---------------------------------------------------------------------------
extern "C" void kernel_launch(void* const* d_in, const int* in_sizes, int n_in,
                              void* d_out, int out_size, void* d_ws,
                              size_t ws_size, hipStream_t stream) {
  const float* nf   = (const float*)d_in[0];
  const float* ef0  = (const float*)d_in[1];
  const float* ef1  = (const float*)d_in[2];
  const float* n_w0 = (const float*)d_in[3];  const float* n_b0 = (const float*)d_in[4];
  const float* n_w1 = (const float*)d_in[5];  const float* n_b1 = (const float*)d_in[6];
  const float* n_w2 = (const float*)d_in[7];  const float* n_b2 = (const float*)d_in[8];
  const float* e0w0 = (const float*)d_in[9];  const float* e0b0 = (const float*)d_in[10];
  const float* e0w1 = (const float*)d_in[11]; const float* e0b1 = (const float*)d_in[12];
  const float* e0w2 = (const float*)d_in[13]; const float* e0b2 = (const float*)d_in[14];
  const float* e1w0 = (const float*)d_in[15]; const float* e1b0 = (const float*)d_in[16];
  const float* e1w1 = (const float*)d_in[17]; const float* e1b1 = (const float*)d_in[18];
  const float* e1w2 = (const float*)d_in[19]; const float* e1b2 = (const float*)d_in[20];
  const float* c1w  = (const float*)d_in[21]; const float* c1b  = (const float*)d_in[22];
  const float* c2w  = (const float*)d_in[23]; const float* c2b  = (const float*)d_in[24];
  const int* src = (const int*)d_in[25];
  const int* dst = (const int*)d_in[26];
  float* out = (float*)d_out;
  float* ws = (float*)d_ws;

  // ---- workspace layout (4B units), total 57,060,000 (= 228.24 MB) ----
  float* hn     = ws;                       // 3,200,000
  float* sbuf   = ws + 3200000;             // 50,000
  int*   rowptr = (int*)(ws + 3250000);     // 50,001
  int*   cntI   = (int*)(ws + 3300008);     // 50,000 (cntI,cntO,fill contiguous)
  int*   cntO   = (int*)(ws + 3350008);     // 50,000
  int*   fill   = (int*)(ws + 3400008);     // 50,000
  int*   bsum   = (int*)(ws + 3450008);     // 256
  int*   boff   = (int*)(ws + 3450264);     // 256
  int*   eslot  = (int*)(ws + 3460000);     // 800,000
  int*   csrc   = (int*)(ws + 4260000);     // 800,000
  float* cnrm   = ws + 5060000;             // 800,000
  float* msg    = ws + 5860000;             // 51,200,000 -> end 57,060,000

  const int NB = (N_NODES + 255) / 256;  // 196

  hipMemsetAsync(cntI, 0, (size_t)3 * N_NODES * sizeof(int), stream);
  count_k<<<(NE + 255) / 256, 256, 0, stream>>>(src, dst, cntO, cntI);
  scan1_k<<<NB, 256, 0, stream>>>(cntI, rowptr, bsum);
  scan2_k<<<1, 256, 0, stream>>>(bsum, boff, rowptr, NB);
  scan3_k<<<NB, 256, 0, stream>>>(rowptr, boff);
  scatter_k<<<(NE + 255) / 256, 256, 0, stream>>>(src, dst, rowptr, fill,
                                                  cntO, cntI, eslot, csrc, cnrm);
  node_mlp_k<<<(N_NODES + 63) / 64, 256, 0, stream>>>(nf, n_w0, n_b0, n_w1,
                                                      n_b1, n_w2, n_b2, hn);
  edge_mlp_k<16><<<(NE0 + 63) / 64, 256, 0, stream>>>(
      ef0, e0w0, e0b0, e0w1, e0b1, e0w2, e0b2, hn, src, dst, cntO, cntI,
      eslot, msg, NE0, 0);
  edge_mlp_k<8><<<(NE1 + 63) / 64, 256, 0, stream>>>(
      ef1, e1w0, e1b0, e1w1, e1b1, e1w2, e1b2, hn, src, dst, cntO, cntI,
      eslot, msg, NE1, NE0);
  gather_conv1_k<<<(N_NODES + 3) / 4, 256, 0, stream>>>(
      rowptr, cnrm, msg, hn, c1w, c1b, c2w, sbuf);
  conv2_gather_k<<<NB, 256, 0, stream>>>(rowptr, csrc, cnrm, sbuf, c2b, out);
}

// Round 5
// 433.635 us; speedup vs baseline: 33.2120x; 1.1952x over previous
//
#include <hip/hip_runtime.h>

#define N_NODES 50000
#define NE0 500000
#define NE1 300000
#define NE (NE0 + NE1)
#define DD 64
#define BS 68  // hidden-activation LDS row stride (floats); empirically conflict-benign (r4: 2.5e5)

// ---------------------------------------------------------------------------
// Wave-structured MLP, single LDS buffer. lane = row (64 rows/block), wave w
// owns cols [16w,16w+16). First layer reads per-lane register inputs (own ef
// row, coalesced 64B); hidden layers read own LDS row via ds_read_b128.
// Weights at W[k*64+wq] are wave-uniform (wq readfirstlane'd) -> SMEM/L1
// broadcast. 16 independent accumulators per lane.
// ---------------------------------------------------------------------------
__device__ __forceinline__ void bias16(const float* __restrict__ B, int wq,
                                       float acc[16]) {
  const float4* bp = (const float4*)(B + wq);
  float4 b0 = bp[0], b1 = bp[1], b2 = bp[2], b3 = bp[3];
  acc[0] = b0.x; acc[1] = b0.y; acc[2] = b0.z; acc[3] = b0.w;
  acc[4] = b1.x; acc[5] = b1.y; acc[6] = b1.z; acc[7] = b1.w;
  acc[8] = b2.x; acc[9] = b2.y; acc[10] = b2.z; acc[11] = b2.w;
  acc[12] = b3.x; acc[13] = b3.y; acc[14] = b3.z; acc[15] = b3.w;
}

__device__ __forceinline__ void fma16(float a, const float* __restrict__ W,
                                      int row, int wq, float acc[16]) {
  const float4* wp = (const float4*)(W + row * DD + wq);
  float4 w0 = wp[0], w1 = wp[1], w2 = wp[2], w3 = wp[3];
  acc[0] = fmaf(a, w0.x, acc[0]);  acc[1] = fmaf(a, w0.y, acc[1]);
  acc[2] = fmaf(a, w0.z, acc[2]);  acc[3] = fmaf(a, w0.w, acc[3]);
  acc[4] = fmaf(a, w1.x, acc[4]);  acc[5] = fmaf(a, w1.y, acc[5]);
  acc[6] = fmaf(a, w1.z, acc[6]);  acc[7] = fmaf(a, w1.w, acc[7]);
  acc[8] = fmaf(a, w2.x, acc[8]);  acc[9] = fmaf(a, w2.y, acc[9]);
  acc[10] = fmaf(a, w2.z, acc[10]); acc[11] = fmaf(a, w2.w, acc[11]);
  acc[12] = fmaf(a, w3.x, acc[12]); acc[13] = fmaf(a, w3.y, acc[13]);
  acc[14] = fmaf(a, w3.z, acc[14]); acc[15] = fmaf(a, w3.w, acc[15]);
}

template <int K>
__device__ __forceinline__ void mlp_regs(const float* __restrict__ x,
                                         const float* __restrict__ W,
                                         const float* __restrict__ Bb, int wq,
                                         float acc[16]) {
  bias16(Bb, wq, acc);
#pragma unroll
  for (int k = 0; k < K; ++k) fma16(x[k], W, k, wq, acc);
}

__device__ __forceinline__ void mlp_lds(const float (*__restrict__ Bf)[BS],
                                        const float* __restrict__ W,
                                        const float* __restrict__ Bb, int lane,
                                        int wq, float acc[16]) {
  bias16(Bb, wq, acc);
#pragma unroll
  for (int k4 = 0; k4 < DD; k4 += 4) {
    float4 a = *(const float4*)(&Bf[lane][k4]);
    fma16(a.x, W, k4 + 0, wq, acc);
    fma16(a.y, W, k4 + 1, wq, acc);
    fma16(a.z, W, k4 + 2, wq, acc);
    fma16(a.w, W, k4 + 3, wq, acc);
  }
}

template <bool RELU>
__device__ __forceinline__ void store16(float (*__restrict__ Bf)[BS], int lane,
                                        int wq, const float acc[16]) {
#pragma unroll
  for (int j = 0; j < 4; ++j) {
    float4 o;
    o.x = RELU ? fmaxf(acc[j * 4 + 0], 0.f) : acc[j * 4 + 0];
    o.y = RELU ? fmaxf(acc[j * 4 + 1], 0.f) : acc[j * 4 + 1];
    o.z = RELU ? fmaxf(acc[j * 4 + 2], 0.f) : acc[j * 4 + 2];
    o.w = RELU ? fmaxf(acc[j * 4 + 3], 0.f) : acc[j * 4 + 3];
    *(float4*)(&Bf[lane][wq + j * 4]) = o;
  }
}

// ============================ CSR build ====================================
__global__ void count_k(const int* __restrict__ src, const int* __restrict__ dst,
                        int* __restrict__ cntO, int* __restrict__ cntI) {
  int e = blockIdx.x * 256 + threadIdx.x;
  if (e < NE) {
    atomicAdd(cntO + src[e], 1);
    atomicAdd(cntI + dst[e], 1);
  }
}

__device__ __forceinline__ int block_scan_excl(int x, int tid, int* total) {
  int lane = tid & 63, w = tid >> 6;
  int incl = x;
#pragma unroll
  for (int d = 1; d < 64; d <<= 1) {
    int y = __shfl_up(incl, d);
    if (lane >= d) incl += y;
  }
  __shared__ int wsum[4];
  if (lane == 63) wsum[w] = incl;
  __syncthreads();
  int woff = 0;
  if (w > 0) woff = wsum[0];
  if (w > 1) woff += wsum[1];
  if (w > 2) woff += wsum[2];
  *total = wsum[0] + wsum[1] + wsum[2] + wsum[3];
  return woff + incl - x;
}

__global__ __launch_bounds__(256) void scan1_k(const int* __restrict__ cnt,
                                               int* __restrict__ rowptr,
                                               int* __restrict__ bsum) {
  int i = blockIdx.x * 256 + threadIdx.x;
  int x = (i < N_NODES) ? cnt[i] : 0;
  int tot;
  int ex = block_scan_excl(x, threadIdx.x, &tot);
  if (i < N_NODES) rowptr[i] = ex;
  if (threadIdx.x == 0) bsum[blockIdx.x] = tot;
}

__global__ __launch_bounds__(256) void scan2_k(const int* __restrict__ bsum,
                                               int* __restrict__ boff,
                                               int* __restrict__ rowptr, int nb) {
  int i = threadIdx.x;
  int x = (i < nb) ? bsum[i] : 0;
  int tot;
  int ex = block_scan_excl(x, i, &tot);
  if (i < nb) boff[i] = ex;
  if (i == 0) rowptr[N_NODES] = tot;
}

__global__ void scan3_k(int* __restrict__ rowptr, const int* __restrict__ boff) {
  int i = blockIdx.x * 256 + threadIdx.x;
  if (i < N_NODES && blockIdx.x > 0) rowptr[i] += boff[blockIdx.x];
}

__global__ void scatter_k(const int* __restrict__ src, const int* __restrict__ dst,
                          const int* __restrict__ rowptr, int* __restrict__ fill,
                          const int* __restrict__ cntO, const int* __restrict__ cntI,
                          int* __restrict__ eslot, int* __restrict__ csrc,
                          float* __restrict__ cnrm) {
  int e = blockIdx.x * 256 + threadIdx.x;
  if (e < NE) {
    int s = src[e], d = dst[e];
    int slot = rowptr[d] + atomicAdd(fill + d, 1);
    eslot[e] = slot;
    csrc[slot] = s;
    cnrm[slot] = rsqrtf((float)max(cntO[s], 1) * (float)max(cntI[d], 1));
  }
}

// ============================ MLP kernels ==================================
__global__ __launch_bounds__(256, 6) void node_mlp_k(
    const float* __restrict__ nf, const float* __restrict__ w0,
    const float* __restrict__ b0, const float* __restrict__ w1,
    const float* __restrict__ b1, const float* __restrict__ w2,
    const float* __restrict__ b2, float* __restrict__ hn) {
  __shared__ float Bf[64][BS];
  int tid = threadIdx.x, lane = tid & 63;
  int wq = __builtin_amdgcn_readfirstlane(tid >> 6) * 16;
  int n = blockIdx.x * 64 + lane;
  float x[32];
#pragma unroll
  for (int i = 0; i < 32; i += 4) {
    float4 v = make_float4(0.f, 0.f, 0.f, 0.f);
    if (n < N_NODES) v = *(const float4*)(nf + (size_t)n * 32 + i);
    x[i] = v.x; x[i + 1] = v.y; x[i + 2] = v.z; x[i + 3] = v.w;
  }
  float acc[16];
  mlp_regs<32>(x, w0, b0, wq, acc);
  store16<true>(Bf, lane, wq, acc);
  __syncthreads();
  mlp_lds(Bf, w1, b1, lane, wq, acc);
  __syncthreads();  // all reads done before overwrite
  store16<true>(Bf, lane, wq, acc);
  __syncthreads();
  mlp_lds(Bf, w2, b2, lane, wq, acc);
  if (n < N_NODES) {
    float* hp = hn + (size_t)n * DD + wq;
#pragma unroll
    for (int j = 0; j < 4; ++j)
      *(float4*)(hp + j * 4) = make_float4(acc[j * 4], acc[j * 4 + 1],
                                           acc[j * 4 + 2], acc[j * 4 + 3]);
  }
}

// Fused edge MLP (both types, block-id split) + u_add_v message + norm,
// written directly to CSR slot order.
template <int FIN>
__device__ __forceinline__ void edge_body(
    float (*__restrict__ Bf)[BS], const float* __restrict__ ef,
    const float* __restrict__ w0, const float* __restrict__ b0,
    const float* __restrict__ w1, const float* __restrict__ b1,
    const float* __restrict__ w2, const float* __restrict__ b2,
    const float* __restrict__ hn, const int* __restrict__ src,
    const int* __restrict__ dst, const int* __restrict__ cntO,
    const int* __restrict__ cntI, const int* __restrict__ eslot,
    float* __restrict__ msg, int e0, int nE, int ebase) {
  int tid = threadIdx.x, lane = tid & 63;
  int wq = __builtin_amdgcn_readfirstlane(tid >> 6) * 16;
  int e = e0 + lane;
  float x[FIN];
#pragma unroll
  for (int i = 0; i < FIN; i += 4) {
    float4 v = make_float4(0.f, 0.f, 0.f, 0.f);
    if (e < nE) v = *(const float4*)(ef + (size_t)e * FIN + i);
    x[i] = v.x; x[i + 1] = v.y; x[i + 2] = v.z; x[i + 3] = v.w;
  }
  float acc[16];
  mlp_regs<FIN>(x, w0, b0, wq, acc);
  store16<true>(Bf, lane, wq, acc);
  __syncthreads();
  mlp_lds(Bf, w1, b1, lane, wq, acc);
  __syncthreads();
  store16<true>(Bf, lane, wq, acc);
  __syncthreads();
  mlp_lds(Bf, w2, b2, lane, wq, acc);  // he chunk (no relu)
  if (e < nE) {
    int ge = ebase + e;
    int slot = eslot[ge];
    int s = src[ge], d = dst[ge];
    float nm = rsqrtf((float)max(cntO[s], 1) * (float)max(cntI[d], 1));
    const float* hs = hn + (size_t)s * DD + wq;
    float* mp = msg + (size_t)slot * DD + wq;
#pragma unroll
    for (int j = 0; j < 4; ++j) {
      float4 h4 = *(const float4*)(hs + j * 4);
      float4 o;
      o.x = (acc[j * 4 + 0] + h4.x) * nm;
      o.y = (acc[j * 4 + 1] + h4.y) * nm;
      o.z = (acc[j * 4 + 2] + h4.z) * nm;
      o.w = (acc[j * 4 + 3] + h4.w) * nm;
      *(float4*)(mp + j * 4) = o;
    }
  }
}

__global__ __launch_bounds__(256, 6) void edge_fused_k(
    const float* __restrict__ ef0, const float* __restrict__ e0w0,
    const float* __restrict__ e0b0, const float* __restrict__ e0w1,
    const float* __restrict__ e0b1, const float* __restrict__ e0w2,
    const float* __restrict__ e0b2, const float* __restrict__ ef1,
    const float* __restrict__ e1w0, const float* __restrict__ e1b0,
    const float* __restrict__ e1w1, const float* __restrict__ e1b1,
    const float* __restrict__ e1w2, const float* __restrict__ e1b2,
    const float* __restrict__ hn, const int* __restrict__ src,
    const int* __restrict__ dst, const int* __restrict__ cntO,
    const int* __restrict__ cntI, const int* __restrict__ eslot,
    float* __restrict__ msg, int NB0v) {
  __shared__ float Bf[64][BS];
  int bid = blockIdx.x;
  if (bid < NB0v)
    edge_body<16>(Bf, ef0, e0w0, e0b0, e0w1, e0b1, e0w2, e0b2, hn, src, dst,
                  cntO, cntI, eslot, msg, bid * 64, NE0, 0);
  else
    edge_body<8>(Bf, ef1, e1w0, e1b0, e1w1, e1b1, e1w2, e1b2, hn, src, dst,
                 cntO, cntI, eslot, msg, (bid - NB0v) * 64, NE1, NE0);
}

// ======================= streaming gather + conv1 ==========================
__global__ __launch_bounds__(256) void gather_conv1_k(
    const int* __restrict__ rowptr, const float* __restrict__ cnrm,
    const float* __restrict__ msg, const float* __restrict__ hn,
    const float* __restrict__ c1w, const float* __restrict__ c1b,
    const float* __restrict__ c2w, float* __restrict__ sbuf) {
  int w = threadIdx.x >> 6, lane = threadIdx.x & 63;
  int n = blockIdx.x * 4 + w;
  if (n >= N_NODES) return;
  int r0 = rowptr[n], r1 = rowptr[n + 1];
  float acc = 0.f, sn = 0.f;
  for (int j = r0; j < r1; ++j) {
    acc += msg[(size_t)j * DD + lane];  // sequential 256B rows
    sn += cnrm[j];
  }
  acc = fmaf(sn, hn[(size_t)n * DD + lane], acc);
  __shared__ float A[4][64];
  A[w][lane] = acc;  // wave-local RAW, no barrier needed
  float h = c1b[lane];
#pragma unroll 8
  for (int k = 0; k < 64; ++k) h = fmaf(A[w][k], c1w[k * DD + lane], h);
  h = fmaxf(h, 0.f);
  float v = h * c2w[lane];
#pragma unroll
  for (int d = 32; d; d >>= 1) v += __shfl_xor(v, d);
  if (lane == 0) sbuf[n] = v;
}

__global__ void conv2_gather_k(const int* __restrict__ rowptr,
                               const int* __restrict__ csrc,
                               const float* __restrict__ cnrm,
                               const float* __restrict__ sbuf,
                               const float* __restrict__ c2b,
                               float* __restrict__ out) {
  int n = blockIdx.x * 256 + threadIdx.x;
  if (n < N_NODES) {
    int r0 = rowptr[n], r1 = rowptr[n + 1];
    float a = 0.f;
    for (int j = r0; j < r1; ++j) a = fmaf(cnrm[j], sbuf[csrc[j]], a);
    out[n] = a + c2b[0];
  }
}

// ---------------------------------------------------------------------------
extern "C" void kernel_launch(void* const* d_in, const int* in_sizes, int n_in,
                              void* d_out, int out_size, void* d_ws,
                              size_t ws_size, hipStream_t stream) {
  const float* nf   = (const float*)d_in[0];
  const float* ef0  = (const float*)d_in[1];
  const float* ef1  = (const float*)d_in[2];
  const float* n_w0 = (const float*)d_in[3];  const float* n_b0 = (const float*)d_in[4];
  const float* n_w1 = (const float*)d_in[5];  const float* n_b1 = (const float*)d_in[6];
  const float* n_w2 = (const float*)d_in[7];  const float* n_b2 = (const float*)d_in[8];
  const float* e0w0 = (const float*)d_in[9];  const float* e0b0 = (const float*)d_in[10];
  const float* e0w1 = (const float*)d_in[11]; const float* e0b1 = (const float*)d_in[12];
  const float* e0w2 = (const float*)d_in[13]; const float* e0b2 = (const float*)d_in[14];
  const float* e1w0 = (const float*)d_in[15]; const float* e1b0 = (const float*)d_in[16];
  const float* e1w1 = (const float*)d_in[17]; const float* e1b1 = (const float*)d_in[18];
  const float* e1w2 = (const float*)d_in[19]; const float* e1b2 = (const float*)d_in[20];
  const float* c1w  = (const float*)d_in[21]; const float* c1b  = (const float*)d_in[22];
  const float* c2w  = (const float*)d_in[23]; const float* c2b  = (const float*)d_in[24];
  const int* src = (const int*)d_in[25];
  const int* dst = (const int*)d_in[26];
  float* out = (float*)d_out;
  float* ws = (float*)d_ws;

  // ---- workspace layout (4B units), total 57,060,000 (= 228.24 MB) ----
  float* hn     = ws;                       // 3,200,000
  float* sbuf   = ws + 3200000;             // 50,000
  int*   rowptr = (int*)(ws + 3250000);     // 50,001
  int*   cntI   = (int*)(ws + 3300008);     // 50,000 (cntI,cntO,fill contiguous)
  int*   cntO   = (int*)(ws + 3350008);     // 50,000
  int*   fill   = (int*)(ws + 3400008);     // 50,000
  int*   bsum   = (int*)(ws + 3450008);     // 256
  int*   boff   = (int*)(ws + 3450264);     // 256
  int*   eslot  = (int*)(ws + 3460000);     // 800,000
  int*   csrc   = (int*)(ws + 4260000);     // 800,000
  float* cnrm   = ws + 5060000;             // 800,000
  float* msg    = ws + 5860000;             // 51,200,000 -> end 57,060,000

  const int NB = (N_NODES + 255) / 256;   // 196
  const int NB0 = (NE0 + 63) / 64;        // 7813
  const int NB1 = (NE1 + 63) / 64;        // 4688

  hipMemsetAsync(cntI, 0, (size_t)3 * N_NODES * sizeof(int), stream);
  count_k<<<(NE + 255) / 256, 256, 0, stream>>>(src, dst, cntO, cntI);
  scan1_k<<<NB, 256, 0, stream>>>(cntI, rowptr, bsum);
  scan2_k<<<1, 256, 0, stream>>>(bsum, boff, rowptr, NB);
  scan3_k<<<NB, 256, 0, stream>>>(rowptr, boff);
  scatter_k<<<(NE + 255) / 256, 256, 0, stream>>>(src, dst, rowptr, fill,
                                                  cntO, cntI, eslot, csrc, cnrm);
  node_mlp_k<<<(N_NODES + 63) / 64, 256, 0, stream>>>(nf, n_w0, n_b0, n_w1,
                                                      n_b1, n_w2, n_b2, hn);
  edge_fused_k<<<NB0 + NB1, 256, 0, stream>>>(
      ef0, e0w0, e0b0, e0w1, e0b1, e0w2, e0b2, ef1, e1w0, e1b0, e1w1, e1b1,
      e1w2, e1b2, hn, src, dst, cntO, cntI, eslot, msg, NB0);
  gather_conv1_k<<<(N_NODES + 3) / 4, 256, 0, stream>>>(
      rowptr, cnrm, msg, hn, c1w, c1b, c2w, sbuf);
  conv2_gather_k<<<NB, 256, 0, stream>>>(rowptr, csrc, cnrm, sbuf, c2b, out);
}

// Round 6
// 305.947 us; speedup vs baseline: 47.0730x; 1.4174x over previous
//
#include <hip/hip_runtime.h>

#define N_NODES 50000
#define NE0 500000
#define NE1 300000
#define NE (NE0 + NE1)
#define DD 64
#define BS 68  // fp32 node-MLP LDS row stride

typedef __bf16 bf16x8 __attribute__((ext_vector_type(8)));
typedef float f32x4 __attribute__((ext_vector_type(4)));

__device__ __forceinline__ ushort f2bf(float x) {  // RNE f32->bf16
  union { float f; unsigned u; } v; v.f = x;
  unsigned r = v.u + 0x7FFFu + ((v.u >> 16) & 1u);
  return (ushort)(r >> 16);
}
__device__ __forceinline__ float bf2f(ushort u) {
  union { unsigned u; float f; } v; v.u = ((unsigned)u) << 16;
  return v.f;
}

// ============================ CSR build ====================================
__global__ void count_k(const int* __restrict__ src, const int* __restrict__ dst,
                        int* __restrict__ cntO, int* __restrict__ cntI) {
  int e = blockIdx.x * 256 + threadIdx.x;
  if (e < NE) {
    atomicAdd(cntO + src[e], 1);
    atomicAdd(cntI + dst[e], 1);
  }
}

__device__ __forceinline__ int block_scan_excl(int x, int tid, int* total) {
  int lane = tid & 63, w = tid >> 6;
  int incl = x;
#pragma unroll
  for (int d = 1; d < 64; d <<= 1) {
    int y = __shfl_up(incl, d);
    if (lane >= d) incl += y;
  }
  __shared__ int wsum[4];
  if (lane == 63) wsum[w] = incl;
  __syncthreads();
  int woff = 0;
  if (w > 0) woff = wsum[0];
  if (w > 1) woff += wsum[1];
  if (w > 2) woff += wsum[2];
  *total = wsum[0] + wsum[1] + wsum[2] + wsum[3];
  return woff + incl - x;
}

__global__ __launch_bounds__(256) void scan1_k(const int* __restrict__ cnt,
                                               int* __restrict__ rowptr,
                                               int* __restrict__ bsum) {
  int i = blockIdx.x * 256 + threadIdx.x;
  int x = (i < N_NODES) ? cnt[i] : 0;
  int tot;
  int ex = block_scan_excl(x, threadIdx.x, &tot);
  if (i < N_NODES) rowptr[i] = ex;
  if (threadIdx.x == 0) bsum[blockIdx.x] = tot;
}

__global__ __launch_bounds__(256) void scan2_k(const int* __restrict__ bsum,
                                               int* __restrict__ boff,
                                               int* __restrict__ rowptr, int nb) {
  int i = threadIdx.x;
  int x = (i < nb) ? bsum[i] : 0;
  int tot;
  int ex = block_scan_excl(x, i, &tot);
  if (i < nb) boff[i] = ex;
  if (i == 0) rowptr[N_NODES] = tot;
}

__global__ void scan3_k(int* __restrict__ rowptr, const int* __restrict__ boff) {
  int i = blockIdx.x * 256 + threadIdx.x;
  if (i < N_NODES && blockIdx.x > 0) rowptr[i] += boff[blockIdx.x];
}

__global__ void scatter_k(const int* __restrict__ src, const int* __restrict__ dst,
                          const int* __restrict__ rowptr, int* __restrict__ fill,
                          const int* __restrict__ cntO, const int* __restrict__ cntI,
                          int* __restrict__ eslot, int* __restrict__ csrc,
                          float* __restrict__ cnrm) {
  int e = blockIdx.x * 256 + threadIdx.x;
  if (e < NE) {
    int s = src[e], d = dst[e];
    int slot = rowptr[d] + atomicAdd(fill + d, 1);
    eslot[e] = slot;
    csrc[slot] = s;
    cnrm[slot] = rsqrtf((float)max(cntO[s], 1) * (float)max(cntI[d], 1));
  }
}

// ================== weight pre-pack into MFMA B-frag order =================
// Frag f, lane l, elem e holds bf16(W[k][n]) with k = ks*32 + (l>>4)*8 + e,
// n = nt*16 + (l&15); zero when k >= K. Layout per type: L1 frags[4] (K<=16
// padded to 32), L2 frags[8] (nt*2+ks), L3 frags[8]. Type1 at +20 frags.
__global__ void pack_k(const float* __restrict__ w00, const float* __restrict__ w01,
                       const float* __restrict__ w02, const float* __restrict__ w10,
                       const float* __restrict__ w11, const float* __restrict__ w12,
                       ushort* __restrict__ pk) {
  int f = blockIdx.x, l = threadIdx.x;  // 40 blocks x 64 threads
  int t = (f >= 20) ? 1 : 0, fl = f - t * 20;
  int layer, nt, ks;
  if (fl < 4) { layer = 0; nt = fl; ks = 0; }
  else if (fl < 12) { layer = 1; nt = (fl - 4) >> 1; ks = (fl - 4) & 1; }
  else { layer = 2; nt = (fl - 12) >> 1; ks = (fl - 12) & 1; }
  const float* W = t ? (layer == 0 ? w10 : (layer == 1 ? w11 : w12))
                     : (layer == 0 ? w00 : (layer == 1 ? w01 : w02));
  int K = (layer == 0) ? (t ? 8 : 16) : 64;
  int g = l >> 4, c = l & 15;
  ushort o[8];
#pragma unroll
  for (int e = 0; e < 8; ++e) {
    int k = ks * 32 + g * 8 + e, n = nt * 16 + c;
    o[e] = f2bf((k < K) ? W[k * DD + n] : 0.f);
  }
  ushort4* d4 = (ushort4*)&pk[(size_t)f * 512 + l * 8];
  d4[0] = make_ushort4(o[0], o[1], o[2], o[3]);
  d4[1] = make_ushort4(o[4], o[5], o[6], o[7]);
}

// ===================== node MLP (fp32, round-5 proven) =====================
__device__ __forceinline__ void bias16(const float* __restrict__ B, int wq,
                                       float acc[16]) {
  const float4* bp = (const float4*)(B + wq);
  float4 b0 = bp[0], b1 = bp[1], b2 = bp[2], b3 = bp[3];
  acc[0] = b0.x; acc[1] = b0.y; acc[2] = b0.z; acc[3] = b0.w;
  acc[4] = b1.x; acc[5] = b1.y; acc[6] = b1.z; acc[7] = b1.w;
  acc[8] = b2.x; acc[9] = b2.y; acc[10] = b2.z; acc[11] = b2.w;
  acc[12] = b3.x; acc[13] = b3.y; acc[14] = b3.z; acc[15] = b3.w;
}

__device__ __forceinline__ void fma16(float a, const float* __restrict__ W,
                                      int row, int wq, float acc[16]) {
  const float4* wp = (const float4*)(W + row * DD + wq);
  float4 w0 = wp[0], w1 = wp[1], w2 = wp[2], w3 = wp[3];
  acc[0] = fmaf(a, w0.x, acc[0]);  acc[1] = fmaf(a, w0.y, acc[1]);
  acc[2] = fmaf(a, w0.z, acc[2]);  acc[3] = fmaf(a, w0.w, acc[3]);
  acc[4] = fmaf(a, w1.x, acc[4]);  acc[5] = fmaf(a, w1.y, acc[5]);
  acc[6] = fmaf(a, w1.z, acc[6]);  acc[7] = fmaf(a, w1.w, acc[7]);
  acc[8] = fmaf(a, w2.x, acc[8]);  acc[9] = fmaf(a, w2.y, acc[9]);
  acc[10] = fmaf(a, w2.z, acc[10]); acc[11] = fmaf(a, w2.w, acc[11]);
  acc[12] = fmaf(a, w3.x, acc[12]); acc[13] = fmaf(a, w3.y, acc[13]);
  acc[14] = fmaf(a, w3.z, acc[14]); acc[15] = fmaf(a, w3.w, acc[15]);
}

__global__ __launch_bounds__(256, 6) void node_mlp_k(
    const float* __restrict__ nf, const float* __restrict__ w0,
    const float* __restrict__ b0, const float* __restrict__ w1,
    const float* __restrict__ b1, const float* __restrict__ w2,
    const float* __restrict__ b2, float* __restrict__ hn) {
  __shared__ float Bf[64][BS];
  int tid = threadIdx.x, lane = tid & 63;
  int wq = __builtin_amdgcn_readfirstlane(tid >> 6) * 16;
  int n = blockIdx.x * 64 + lane;
  float x[32];
#pragma unroll
  for (int i = 0; i < 32; i += 4) {
    float4 v = make_float4(0.f, 0.f, 0.f, 0.f);
    if (n < N_NODES) v = *(const float4*)(nf + (size_t)n * 32 + i);
    x[i] = v.x; x[i + 1] = v.y; x[i + 2] = v.z; x[i + 3] = v.w;
  }
  float acc[16];
  bias16(b0, wq, acc);
#pragma unroll
  for (int k = 0; k < 32; ++k) fma16(x[k], w0, k, wq, acc);
#pragma unroll
  for (int j = 0; j < 4; ++j) {
    float4 o;
    o.x = fmaxf(acc[j * 4 + 0], 0.f); o.y = fmaxf(acc[j * 4 + 1], 0.f);
    o.z = fmaxf(acc[j * 4 + 2], 0.f); o.w = fmaxf(acc[j * 4 + 3], 0.f);
    *(float4*)(&Bf[lane][wq + j * 4]) = o;
  }
  __syncthreads();
  bias16(b1, wq, acc);
#pragma unroll
  for (int k4 = 0; k4 < DD; k4 += 4) {
    float4 a = *(const float4*)(&Bf[lane][k4]);
    fma16(a.x, w1, k4 + 0, wq, acc);
    fma16(a.y, w1, k4 + 1, wq, acc);
    fma16(a.z, w1, k4 + 2, wq, acc);
    fma16(a.w, w1, k4 + 3, wq, acc);
  }
  __syncthreads();
#pragma unroll
  for (int j = 0; j < 4; ++j) {
    float4 o;
    o.x = fmaxf(acc[j * 4 + 0], 0.f); o.y = fmaxf(acc[j * 4 + 1], 0.f);
    o.z = fmaxf(acc[j * 4 + 2], 0.f); o.w = fmaxf(acc[j * 4 + 3], 0.f);
    *(float4*)(&Bf[lane][wq + j * 4]) = o;
  }
  __syncthreads();
  bias16(b2, wq, acc);
#pragma unroll
  for (int k4 = 0; k4 < DD; k4 += 4) {
    float4 a = *(const float4*)(&Bf[lane][k4]);
    fma16(a.x, w2, k4 + 0, wq, acc);
    fma16(a.y, w2, k4 + 1, wq, acc);
    fma16(a.z, w2, k4 + 2, wq, acc);
    fma16(a.w, w2, k4 + 3, wq, acc);
  }
  if (n < N_NODES) {
    float* hp = hn + (size_t)n * DD + wq;
#pragma unroll
    for (int j = 0; j < 4; ++j)
      *(float4*)(hp + j * 4) = make_float4(acc[j * 4], acc[j * 4 + 1],
                                           acc[j * 4 + 2], acc[j * 4 + 3]);
  }
}

// ===================== edge MLP via bf16 MFMA (fused) ======================
// Per wave: 16 edges, fully independent (no __syncthreads anywhere).
// A-frag: lane l holds A[m=l&15][k=(l>>4)*8+i] from per-wave LDS [16][72] bf16.
// B-frag: pre-packed frag stream (coalesced 1KB, L2-resident).
// D-frag: lane l holds D[m=(l>>4)*4+r][n=nt*16+(l&15)] (m89-verified map).
template <int FIN>
__device__ __forceinline__ void edge_body_mfma(
    ushort (*__restrict__ act)[16][72], const float* __restrict__ ef,
    const ushort* __restrict__ pk, int pkb, const float* __restrict__ B0,
    const float* __restrict__ B1, const float* __restrict__ B2,
    const float* __restrict__ hn, const int* __restrict__ src,
    const int* __restrict__ dst, const int* __restrict__ cntO,
    const int* __restrict__ cntI, const int* __restrict__ eslot,
    ushort* __restrict__ msg, int e0, int nE, int ebase) {
  const int tid = threadIdx.x, wid = tid >> 6, l = tid & 63;
  const int g = l >> 4, c = l & 15;
  ushort (*__restrict__ A)[72] = act[wid];
  const int ew = e0 + wid * 16;

  // ---- stage this wave's 16 input rows (bf16), coalesced ----
  {
    int row = l >> 2;
    int e = ew + row;
    if (FIN == 16) {
      int cq = (l & 3) * 4;
      float4 v = make_float4(0.f, 0.f, 0.f, 0.f);
      if (e < nE) v = *(const float4*)(ef + (size_t)e * 16 + cq);
      ushort4 o;
      o.x = f2bf(v.x); o.y = f2bf(v.y); o.z = f2bf(v.z); o.w = f2bf(v.w);
      *(ushort4*)&A[row][cq] = o;
    } else {
      int cq = (l & 3) * 2;
      float2 v = make_float2(0.f, 0.f);
      if (e < nE) v = *(const float2*)(ef + (size_t)e * 8 + cq);
      ushort2 o;
      o.x = f2bf(v.x); o.y = f2bf(v.y);
      *(ushort2*)&A[row][cq] = o;
    }
  }
  // ---- per-row meta in lanes 0..15 (pulled later via shfl) ----
  int sv = 0, slv = 0;
  float nmv = 0.f;
  if (l < 16) {
    int e = ew + l;
    if (e < nE) {
      int ge = ebase + e;
      sv = src[ge];
      int d = dst[ge];
      slv = eslot[ge];
      nmv = rsqrtf((float)max(cntO[sv], 1) * (float)max(cntI[d], 1));
    }
  }
  asm volatile("s_waitcnt lgkmcnt(0)" ::: "memory");  // same-wave LDS RAW

  f32x4 acc[4];
  // ===== L1 (K padded to 32; lane-groups with k>=FIN are zero) =====
#pragma unroll
  for (int nt = 0; nt < 4; ++nt) {
    float b = B0[nt * 16 + c];
    acc[nt] = f32x4{b, b, b, b};
  }
  {
    bf16x8 a0 = {};
    if (g * 8 < FIN) a0 = *(const bf16x8*)&A[c][g * 8];
#pragma unroll
    for (int nt = 0; nt < 4; ++nt) {
      bf16x8 bb = *(const bf16x8*)&pk[(size_t)(pkb + nt) * 512 + l * 8];
      acc[nt] = __builtin_amdgcn_mfma_f32_16x16x32_bf16(a0, bb, acc[nt], 0, 0, 0);
    }
  }
#pragma unroll
  for (int nt = 0; nt < 4; ++nt)
#pragma unroll
    for (int r = 0; r < 4; ++r)
      A[g * 4 + r][nt * 16 + c] = f2bf(fmaxf(acc[nt][r], 0.f));
  asm volatile("s_waitcnt lgkmcnt(0)" ::: "memory");

  // ===== L2 (K=64: 2 k-steps) =====
#pragma unroll
  for (int nt = 0; nt < 4; ++nt) {
    float b = B1[nt * 16 + c];
    acc[nt] = f32x4{b, b, b, b};
  }
  {
    bf16x8 x0 = *(const bf16x8*)&A[c][g * 8];
    bf16x8 x1 = *(const bf16x8*)&A[c][32 + g * 8];
#pragma unroll
    for (int nt = 0; nt < 4; ++nt) {
      bf16x8 bb0 = *(const bf16x8*)&pk[(size_t)(pkb + 4 + nt * 2) * 512 + l * 8];
      bf16x8 bb1 = *(const bf16x8*)&pk[(size_t)(pkb + 5 + nt * 2) * 512 + l * 8];
      acc[nt] = __builtin_amdgcn_mfma_f32_16x16x32_bf16(x0, bb0, acc[nt], 0, 0, 0);
      acc[nt] = __builtin_amdgcn_mfma_f32_16x16x32_bf16(x1, bb1, acc[nt], 0, 0, 0);
    }
  }
#pragma unroll
  for (int nt = 0; nt < 4; ++nt)
#pragma unroll
    for (int r = 0; r < 4; ++r)
      A[g * 4 + r][nt * 16 + c] = f2bf(fmaxf(acc[nt][r], 0.f));
  asm volatile("s_waitcnt lgkmcnt(0)" ::: "memory");

  // ===== L3 (K=64, no relu; result stays in D-frags) =====
#pragma unroll
  for (int nt = 0; nt < 4; ++nt) {
    float b = B2[nt * 16 + c];
    acc[nt] = f32x4{b, b, b, b};
  }
  {
    bf16x8 x0 = *(const bf16x8*)&A[c][g * 8];
    bf16x8 x1 = *(const bf16x8*)&A[c][32 + g * 8];
#pragma unroll
    for (int nt = 0; nt < 4; ++nt) {
      bf16x8 bb0 = *(const bf16x8*)&pk[(size_t)(pkb + 12 + nt * 2) * 512 + l * 8];
      bf16x8 bb1 = *(const bf16x8*)&pk[(size_t)(pkb + 13 + nt * 2) * 512 + l * 8];
      acc[nt] = __builtin_amdgcn_mfma_f32_16x16x32_bf16(x0, bb0, acc[nt], 0, 0, 0);
      acc[nt] = __builtin_amdgcn_mfma_f32_16x16x32_bf16(x1, bb1, acc[nt], 0, 0, 0);
    }
  }

  // ===== epilogue: msg[slot] = bf16( (he + hn[src]) * nm ), D-frag direct ====
  int srow[4], slot4[4];
  float nm4[4];
#pragma unroll
  for (int r = 0; r < 4; ++r) {
    int rr = g * 4 + r;
    srow[r] = __shfl(sv, rr);
    slot4[r] = __shfl(slv, rr);
    nm4[r] = __shfl(nmv, rr);
  }
#pragma unroll
  for (int r = 0; r < 4; ++r) {
    if (ew + g * 4 + r < nE) {
      const float* hp = hn + (size_t)srow[r] * DD + c;
      ushort* mp = msg + (size_t)slot4[r] * DD + c;
#pragma unroll
      for (int nt = 0; nt < 4; ++nt)
        mp[nt * 16] = f2bf((acc[nt][r] + hp[nt * 16]) * nm4[r]);
    }
  }
}

__global__ __launch_bounds__(256, 6) void edge_mfma_k(
    const float* __restrict__ ef0, const float* __restrict__ ef1,
    const ushort* __restrict__ pk, const float* __restrict__ b00,
    const float* __restrict__ b01, const float* __restrict__ b02,
    const float* __restrict__ b10, const float* __restrict__ b11,
    const float* __restrict__ b12, const float* __restrict__ hn,
    const int* __restrict__ src, const int* __restrict__ dst,
    const int* __restrict__ cntO, const int* __restrict__ cntI,
    const int* __restrict__ eslot, ushort* __restrict__ msg, int NB0v) {
  __shared__ __align__(16) ushort act[4][16][72];
  int bid = blockIdx.x;
  if (bid < NB0v)
    edge_body_mfma<16>(act, ef0, pk, 0, b00, b01, b02, hn, src, dst, cntO,
                       cntI, eslot, msg, bid * 64, NE0, 0);
  else
    edge_body_mfma<8>(act, ef1, pk, 20, b10, b11, b12, hn, src, dst, cntO,
                      cntI, eslot, msg, (bid - NB0v) * 64, NE1, NE0);
}

// ======================= streaming gather + conv1 ==========================
__global__ __launch_bounds__(256) void gather_conv1_k(
    const int* __restrict__ rowptr, const float* __restrict__ cnrm,
    const ushort* __restrict__ msgb, const float* __restrict__ hn,
    const float* __restrict__ c1w, const float* __restrict__ c1b,
    const float* __restrict__ c2w, float* __restrict__ sbuf) {
  int w = threadIdx.x >> 6, lane = threadIdx.x & 63;
  int n = blockIdx.x * 4 + w;
  if (n >= N_NODES) return;
  int r0 = rowptr[n], r1 = rowptr[n + 1];
  float acc = 0.f, sn = 0.f;
  for (int j = r0; j < r1; ++j) {
    acc += bf2f(msgb[(size_t)j * DD + lane]);  // sequential 128B rows
    sn += cnrm[j];
  }
  acc = fmaf(sn, hn[(size_t)n * DD + lane], acc);
  __shared__ float A[4][64];
  A[w][lane] = acc;  // wave-local RAW (HW-proven pattern, rounds 3-5)
  float h = c1b[lane];
#pragma unroll 8
  for (int k = 0; k < 64; ++k) h = fmaf(A[w][k], c1w[k * DD + lane], h);
  h = fmaxf(h, 0.f);
  float v = h * c2w[lane];
#pragma unroll
  for (int d = 32; d; d >>= 1) v += __shfl_xor(v, d);
  if (lane == 0) sbuf[n] = v;
}

__global__ void conv2_gather_k(const int* __restrict__ rowptr,
                               const int* __restrict__ csrc,
                               const float* __restrict__ cnrm,
                               const float* __restrict__ sbuf,
                               const float* __restrict__ c2b,
                               float* __restrict__ out) {
  int n = blockIdx.x * 256 + threadIdx.x;
  if (n < N_NODES) {
    int r0 = rowptr[n], r1 = rowptr[n + 1];
    float a = 0.f;
    for (int j = r0; j < r1; ++j) a = fmaf(cnrm[j], sbuf[csrc[j]], a);
    out[n] = a + c2b[0];
  }
}

// ---------------------------------------------------------------------------
extern "C" void kernel_launch(void* const* d_in, const int* in_sizes, int n_in,
                              void* d_out, int out_size, void* d_ws,
                              size_t ws_size, hipStream_t stream) {
  const float* nf   = (const float*)d_in[0];
  const float* ef0  = (const float*)d_in[1];
  const float* ef1  = (const float*)d_in[2];
  const float* n_w0 = (const float*)d_in[3];  const float* n_b0 = (const float*)d_in[4];
  const float* n_w1 = (const float*)d_in[5];  const float* n_b1 = (const float*)d_in[6];
  const float* n_w2 = (const float*)d_in[7];  const float* n_b2 = (const float*)d_in[8];
  const float* e0w0 = (const float*)d_in[9];  const float* e0b0 = (const float*)d_in[10];
  const float* e0w1 = (const float*)d_in[11]; const float* e0b1 = (const float*)d_in[12];
  const float* e0w2 = (const float*)d_in[13]; const float* e0b2 = (const float*)d_in[14];
  const float* e1w0 = (const float*)d_in[15]; const float* e1b0 = (const float*)d_in[16];
  const float* e1w1 = (const float*)d_in[17]; const float* e1b1 = (const float*)d_in[18];
  const float* e1w2 = (const float*)d_in[19]; const float* e1b2 = (const float*)d_in[20];
  const float* c1w  = (const float*)d_in[21]; const float* c1b  = (const float*)d_in[22];
  const float* c2w  = (const float*)d_in[23]; const float* c2b  = (const float*)d_in[24];
  const int* src = (const int*)d_in[25];
  const int* dst = (const int*)d_in[26];
  float* out = (float*)d_out;
  float* ws = (float*)d_ws;

  // ---- workspace layout (4B units) ----
  float*  hn     = ws;                        // 3,200,000
  float*  sbuf   = ws + 3200000;              // 50,000
  int*    rowptr = (int*)(ws + 3250000);      // 50,001
  int*    cntI   = (int*)(ws + 3300008);      // 50,000 (cntI,cntO,fill contiguous)
  int*    cntO   = (int*)(ws + 3350008);      // 50,000
  int*    fill   = (int*)(ws + 3400008);      // 50,000
  int*    bsum   = (int*)(ws + 3450008);      // 256
  int*    boff   = (int*)(ws + 3450264);      // 256
  int*    eslot  = (int*)(ws + 3460000);      // 800,000
  int*    csrc   = (int*)(ws + 4260000);      // 800,000
  float*  cnrm   = ws + 5060000;              // 800,000
  ushort* msg    = (ushort*)(ws + 5860000);   // 51.2M ushorts -> +25.6M floats
  ushort* pk     = (ushort*)(ws + 31500000);  // 20,480 ushorts
  // total ~31.52M floats = 126 MB

  const int NB = (N_NODES + 255) / 256;   // 196
  const int NB0 = (NE0 + 63) / 64;        // 7813
  const int NB1 = (NE1 + 63) / 64;        // 4688

  hipMemsetAsync(cntI, 0, (size_t)3 * N_NODES * sizeof(int), stream);
  pack_k<<<40, 64, 0, stream>>>(e0w0, e0w1, e0w2, e1w0, e1w1, e1w2, pk);
  count_k<<<(NE + 255) / 256, 256, 0, stream>>>(src, dst, cntO, cntI);
  scan1_k<<<NB, 256, 0, stream>>>(cntI, rowptr, bsum);
  scan2_k<<<1, 256, 0, stream>>>(bsum, boff, rowptr, NB);
  scan3_k<<<NB, 256, 0, stream>>>(rowptr, boff);
  scatter_k<<<(NE + 255) / 256, 256, 0, stream>>>(src, dst, rowptr, fill,
                                                  cntO, cntI, eslot, csrc, cnrm);
  node_mlp_k<<<(N_NODES + 63) / 64, 256, 0, stream>>>(nf, n_w0, n_b0, n_w1,
                                                      n_b1, n_w2, n_b2, hn);
  edge_mfma_k<<<NB0 + NB1, 256, 0, stream>>>(
      ef0, ef1, pk, e0b0, e0b1, e0b2, e1b0, e1b1, e1b2, hn, src, dst, cntO,
      cntI, eslot, msg, NB0);
  gather_conv1_k<<<(N_NODES + 3) / 4, 256, 0, stream>>>(
      rowptr, cnrm, msg, hn, c1w, c1b, c2w, sbuf);
  conv2_gather_k<<<NB, 256, 0, stream>>>(rowptr, csrc, cnrm, sbuf, c2b, out);
}

// Round 7
// 289.280 us; speedup vs baseline: 49.7853x; 1.0576x over previous
//
#include <hip/hip_runtime.h>

#define N_NODES 50000
#define NE0 500000
#define NE1 300000
#define NE (NE0 + NE1)
#define DD 64

typedef __bf16 bf16x8 __attribute__((ext_vector_type(8)));
typedef float f32x4 __attribute__((ext_vector_type(4)));

__device__ __forceinline__ ushort f2bf(float x) {  // RNE via native cvt
  union { __bf16 h; ushort u; } v;
  v.h = (__bf16)x;
  return v.u;
}
__device__ __forceinline__ float bf2f(ushort u) {
  union { unsigned u; float f; } v;
  v.u = ((unsigned)u) << 16;
  return v.f;
}

// rowptr finalization: scan1 leaves per-block partial sums, boff[b] is the
// block offset. Inline instead of a 50K-thread fixup dispatch.
__device__ __forceinline__ int RP(const int* __restrict__ rowptr,
                                  const int* __restrict__ boff, int i) {
  return (i >= N_NODES) ? NE : rowptr[i] + boff[i >> 8];
}

// ==================== fused pack(60) + count(3126) =========================
// pack: B-frag order for mfma_f32_16x16x32_bf16: frag f, lane l, elem e ->
// W[k][n], k = ks*32 + (l>>4)*8 + e, n = nt*16 + (l&15), zero for k >= K.
// Per type: L1 frags 0..3 (nt), L2 frags 4..11 (nt*2+ks), L3 12..19.
// Types: 0=edge16 (pkb 0), 1=edge8 (pkb 20), 2=node32 (pkb 40).
__global__ void prep_k(const float* __restrict__ w00, const float* __restrict__ w01,
                       const float* __restrict__ w02, const float* __restrict__ w10,
                       const float* __restrict__ w11, const float* __restrict__ w12,
                       const float* __restrict__ w20, const float* __restrict__ w21,
                       const float* __restrict__ w22, ushort* __restrict__ pk,
                       const int* __restrict__ src, const int* __restrict__ dst,
                       int* __restrict__ cntO, int* __restrict__ cntI) {
  int bid = blockIdx.x, tid = threadIdx.x;
  if (bid < 60) {
    if (tid >= 64) return;
    int t = bid / 20, fl = bid % 20, l = tid;
    int layer, nt, ks;
    if (fl < 4) { layer = 0; nt = fl; ks = 0; }
    else if (fl < 12) { layer = 1; nt = (fl - 4) >> 1; ks = (fl - 4) & 1; }
    else { layer = 2; nt = (fl - 12) >> 1; ks = (fl - 12) & 1; }
    const float* Wt[3][3] = {{w00, w01, w02}, {w10, w11, w12}, {w20, w21, w22}};
    const int K0[3] = {16, 8, 32};
    const float* W = Wt[t][layer];
    int K = (layer == 0) ? K0[t] : 64;
    int g = l >> 4, c = l & 15;
    ushort o[8];
#pragma unroll
    for (int e = 0; e < 8; ++e) {
      int k = ks * 32 + g * 8 + e, n = nt * 16 + c;
      o[e] = f2bf((k < K) ? W[k * DD + n] : 0.f);
    }
    ushort4* d4 = (ushort4*)&pk[(size_t)bid * 512 + l * 8];
    d4[0] = make_ushort4(o[0], o[1], o[2], o[3]);
    d4[1] = make_ushort4(o[4], o[5], o[6], o[7]);
  } else {
    int e = (bid - 60) * 256 + tid;
    if (e < NE) {
      atomicAdd(cntO + src[e], 1);
      atomicAdd(cntI + dst[e], 1);
    }
  }
}

// ============================ scans ========================================
__device__ __forceinline__ int block_scan_excl(int x, int tid, int* total) {
  int lane = tid & 63, w = tid >> 6;
  int incl = x;
#pragma unroll
  for (int d = 1; d < 64; d <<= 1) {
    int y = __shfl_up(incl, d);
    if (lane >= d) incl += y;
  }
  __shared__ int wsum[4];
  if (lane == 63) wsum[w] = incl;
  __syncthreads();
  int woff = 0;
  if (w > 0) woff = wsum[0];
  if (w > 1) woff += wsum[1];
  if (w > 2) woff += wsum[2];
  *total = wsum[0] + wsum[1] + wsum[2] + wsum[3];
  return woff + incl - x;
}

__global__ __launch_bounds__(256) void scan1_k(const int* __restrict__ cnt,
                                               int* __restrict__ rowptr,
                                               int* __restrict__ bsum) {
  int i = blockIdx.x * 256 + threadIdx.x;
  int x = (i < N_NODES) ? cnt[i] : 0;
  int tot;
  int ex = block_scan_excl(x, threadIdx.x, &tot);
  if (i < N_NODES) rowptr[i] = ex;
  if (threadIdx.x == 0) bsum[blockIdx.x] = tot;
}

__global__ __launch_bounds__(256) void scan2_k(const int* __restrict__ bsum,
                                               int* __restrict__ boff, int nb) {
  int i = threadIdx.x;
  int x = (i < nb) ? bsum[i] : 0;
  int tot;
  int ex = block_scan_excl(x, i, &tot);
  if (i < nb) boff[i] = ex;
}

__global__ void scatter_k(const int* __restrict__ src, const int* __restrict__ dst,
                          const int* __restrict__ rowptr, const int* __restrict__ boff,
                          int* __restrict__ fill, const int* __restrict__ cntO,
                          const int* __restrict__ cntI, int* __restrict__ eslot,
                          int* __restrict__ csrc, float* __restrict__ cnrm,
                          float* __restrict__ nmE) {
  int e = blockIdx.x * 256 + threadIdx.x;
  if (e < NE) {
    int s = src[e], d = dst[e];
    int slot = RP(rowptr, boff, d) + atomicAdd(fill + d, 1);
    float nm = rsqrtf((float)max(cntO[s], 1) * (float)max(cntI[d], 1));
    eslot[e] = slot;
    nmE[e] = nm;   // per-edge, coalesced for the mega kernel
    csrc[slot] = s;
    cnrm[slot] = nm;
  }
}

// ================= mega MFMA kernel: node MLP + both edge MLPs =============
// Per wave: 16 rows, fully independent (zero __syncthreads).
// A-frag: lane l holds A[m=l&15][k=(l>>4)*8+i] from per-wave LDS [16][72] bf16.
// B-frag: pre-packed stream (coalesced 1KB, L2-resident).
// D-frag: lane l holds D[m=(l>>4)*4+r][n=nt*16+(l&15)] (m89-verified map).
template <int FIN, bool NODE>
__device__ __forceinline__ void mlp_body(
    ushort (*__restrict__ A)[72], const float* __restrict__ xin,
    const ushort* __restrict__ pk, int pkb, const float* __restrict__ B0,
    const float* __restrict__ B1, const float* __restrict__ B2,
    const int* __restrict__ eslot, const float* __restrict__ nmE,
    ushort* __restrict__ msg, float* __restrict__ hn, int r0w, int nR,
    int ebase) {
  const int l = threadIdx.x & 63;
  const int g = l >> 4, c = l & 15;

  // ---- stage 16 input rows (bf16), coalesced ----
  {
    int row = l >> 2;
    int r = r0w + row;
    if (FIN == 32) {
      int cq = (l & 3) * 8;
      float4 v0 = make_float4(0.f, 0.f, 0.f, 0.f), v1 = v0;
      if (r < nR) {
        v0 = *(const float4*)(xin + (size_t)r * 32 + cq);
        v1 = *(const float4*)(xin + (size_t)r * 32 + cq + 4);
      }
      *(ushort4*)&A[row][cq] = make_ushort4(f2bf(v0.x), f2bf(v0.y), f2bf(v0.z), f2bf(v0.w));
      *(ushort4*)&A[row][cq + 4] = make_ushort4(f2bf(v1.x), f2bf(v1.y), f2bf(v1.z), f2bf(v1.w));
    } else if (FIN == 16) {
      int cq = (l & 3) * 4;
      float4 v = make_float4(0.f, 0.f, 0.f, 0.f);
      if (r < nR) v = *(const float4*)(xin + (size_t)r * 16 + cq);
      *(ushort4*)&A[row][cq] = make_ushort4(f2bf(v.x), f2bf(v.y), f2bf(v.z), f2bf(v.w));
    } else {
      int cq = (l & 3) * 2;
      float2 v = make_float2(0.f, 0.f);
      if (r < nR) v = *(const float2*)(xin + (size_t)r * 8 + cq);
      *(ushort2*)&A[row][cq] = make_ushort2(f2bf(v.x), f2bf(v.y));
    }
  }
  // ---- per-row meta in lanes 0..15 (edges only) ----
  int slv = 0;
  float nmv = 0.f;
  if (!NODE && l < 16) {
    int e = r0w + l;
    if (e < nR) {
      slv = eslot[ebase + e];
      nmv = nmE[ebase + e];
    }
  }
  asm volatile("s_waitcnt lgkmcnt(0)" ::: "memory");  // same-wave LDS RAW

  f32x4 acc[4];
  // ===== L1 (K padded to 32) =====
#pragma unroll
  for (int nt = 0; nt < 4; ++nt) {
    float b = B0[nt * 16 + c];
    acc[nt] = f32x4{b, b, b, b};
  }
  {
    bf16x8 a0 = {};
    if (g * 8 < FIN) a0 = *(const bf16x8*)&A[c][g * 8];
#pragma unroll
    for (int nt = 0; nt < 4; ++nt) {
      bf16x8 bb = *(const bf16x8*)&pk[(size_t)(pkb + nt) * 512 + l * 8];
      acc[nt] = __builtin_amdgcn_mfma_f32_16x16x32_bf16(a0, bb, acc[nt], 0, 0, 0);
    }
  }
#pragma unroll
  for (int nt = 0; nt < 4; ++nt)
#pragma unroll
    for (int r = 0; r < 4; ++r)
      A[g * 4 + r][nt * 16 + c] = f2bf(fmaxf(acc[nt][r], 0.f));
  asm volatile("s_waitcnt lgkmcnt(0)" ::: "memory");

  // ===== L2 (K=64) =====
#pragma unroll
  for (int nt = 0; nt < 4; ++nt) {
    float b = B1[nt * 16 + c];
    acc[nt] = f32x4{b, b, b, b};
  }
  {
    bf16x8 x0 = *(const bf16x8*)&A[c][g * 8];
    bf16x8 x1 = *(const bf16x8*)&A[c][32 + g * 8];
#pragma unroll
    for (int nt = 0; nt < 4; ++nt) {
      bf16x8 bb0 = *(const bf16x8*)&pk[(size_t)(pkb + 4 + nt * 2) * 512 + l * 8];
      bf16x8 bb1 = *(const bf16x8*)&pk[(size_t)(pkb + 5 + nt * 2) * 512 + l * 8];
      acc[nt] = __builtin_amdgcn_mfma_f32_16x16x32_bf16(x0, bb0, acc[nt], 0, 0, 0);
      acc[nt] = __builtin_amdgcn_mfma_f32_16x16x32_bf16(x1, bb1, acc[nt], 0, 0, 0);
    }
  }
#pragma unroll
  for (int nt = 0; nt < 4; ++nt)
#pragma unroll
    for (int r = 0; r < 4; ++r)
      A[g * 4 + r][nt * 16 + c] = f2bf(fmaxf(acc[nt][r], 0.f));
  asm volatile("s_waitcnt lgkmcnt(0)" ::: "memory");

  // ===== L3 (K=64, no relu) =====
#pragma unroll
  for (int nt = 0; nt < 4; ++nt) {
    float b = B2[nt * 16 + c];
    acc[nt] = f32x4{b, b, b, b};
  }
  {
    bf16x8 x0 = *(const bf16x8*)&A[c][g * 8];
    bf16x8 x1 = *(const bf16x8*)&A[c][32 + g * 8];
#pragma unroll
    for (int nt = 0; nt < 4; ++nt) {
      bf16x8 bb0 = *(const bf16x8*)&pk[(size_t)(pkb + 12 + nt * 2) * 512 + l * 8];
      bf16x8 bb1 = *(const bf16x8*)&pk[(size_t)(pkb + 13 + nt * 2) * 512 + l * 8];
      acc[nt] = __builtin_amdgcn_mfma_f32_16x16x32_bf16(x0, bb0, acc[nt], 0, 0, 0);
      acc[nt] = __builtin_amdgcn_mfma_f32_16x16x32_bf16(x1, bb1, acc[nt], 0, 0, 0);
    }
  }

  // ===== epilogue: D-frag direct =====
  if (NODE) {
#pragma unroll
    for (int r = 0; r < 4; ++r) {
      int n = r0w + g * 4 + r;
      if (n < nR) {
        float* hp = hn + (size_t)n * DD + c;
#pragma unroll
        for (int nt = 0; nt < 4; ++nt) hp[nt * 16] = acc[nt][r];
      }
    }
  } else {
    int slot4[4];
    float nm4[4];
#pragma unroll
    for (int r = 0; r < 4; ++r) {
      int rr = g * 4 + r;
      slot4[r] = __shfl(slv, rr);
      nm4[r] = __shfl(nmv, rr);
    }
#pragma unroll
    for (int r = 0; r < 4; ++r) {
      if (r0w + g * 4 + r < nR) {
        ushort* mp = msg + (size_t)slot4[r] * DD + c;
#pragma unroll
        for (int nt = 0; nt < 4; ++nt) mp[nt * 16] = f2bf(acc[nt][r] * nm4[r]);
      }
    }
  }
}

__global__ __launch_bounds__(256, 6) void mega_mfma_k(
    const float* __restrict__ nf, const float* __restrict__ ef0,
    const float* __restrict__ ef1, const ushort* __restrict__ pk,
    const float* __restrict__ nb0, const float* __restrict__ nb1,
    const float* __restrict__ nb2, const float* __restrict__ b00,
    const float* __restrict__ b01, const float* __restrict__ b02,
    const float* __restrict__ b10, const float* __restrict__ b11,
    const float* __restrict__ b12, const int* __restrict__ eslot,
    const float* __restrict__ nmE, ushort* __restrict__ msg,
    float* __restrict__ hn, int NBn, int NB0v) {
  __shared__ __align__(16) ushort act[4][16][72];
  int bid = blockIdx.x, wid = threadIdx.x >> 6;
  ushort (*A)[72] = act[wid];
  if (bid < NBn) {
    mlp_body<32, true>(A, nf, pk, 40, nb0, nb1, nb2, nullptr, nullptr,
                       nullptr, hn, bid * 64 + wid * 16, N_NODES, 0);
  } else if (bid < NBn + NB0v) {
    mlp_body<16, false>(A, ef0, pk, 0, b00, b01, b02, eslot, nmE, msg,
                        nullptr, (bid - NBn) * 64 + wid * 16, NE0, 0);
  } else {
    mlp_body<8, false>(A, ef1, pk, 20, b10, b11, b12, eslot, nmE, msg,
                       nullptr, (bid - NBn - NB0v) * 64 + wid * 16, NE1, NE0);
  }
}

// ======================= streaming gather + conv1 ==========================
// agg[n] = sum_slots msg(=nm*he) + sum_slots nm*hn[src] + (sum nm)*hn[n]
__global__ __launch_bounds__(256) void gather_conv1_k(
    const int* __restrict__ rowptr, const int* __restrict__ boff,
    const int* __restrict__ csrc, const float* __restrict__ cnrm,
    const ushort* __restrict__ msgb, const float* __restrict__ hn,
    const float* __restrict__ c1w, const float* __restrict__ c1b,
    const float* __restrict__ c2w, float* __restrict__ sbuf) {
  int w = threadIdx.x >> 6, lane = threadIdx.x & 63;
  int n = blockIdx.x * 4 + w;
  if (n >= N_NODES) return;
  int r0 = RP(rowptr, boff, n), r1 = RP(rowptr, boff, n + 1);
  float acc = 0.f, sn = 0.f;
  for (int j = r0; j < r1; ++j) {
    int sv = csrc[j];                     // uniform -> scalar-promoted
    float nm = cnrm[j];
    acc += bf2f(msgb[(size_t)j * DD + lane]);
    acc = fmaf(nm, hn[(size_t)sv * DD + lane], acc);
    sn += nm;
  }
  acc = fmaf(sn, hn[(size_t)n * DD + lane], acc);
  __shared__ float Asm[4][64];
  Asm[w][lane] = acc;  // wave-local RAW (HW-proven, rounds 3-6)
  float h = c1b[lane];
#pragma unroll 8
  for (int k = 0; k < 64; ++k) h = fmaf(Asm[w][k], c1w[k * DD + lane], h);
  h = fmaxf(h, 0.f);
  float v = h * c2w[lane];
#pragma unroll
  for (int d = 32; d; d >>= 1) v += __shfl_xor(v, d);
  if (lane == 0) sbuf[n] = v;
}

// conv2: 16 lanes per node -> parallel loads instead of 16 serial dependent.
__global__ __launch_bounds__(256) void conv2_gather_k(
    const int* __restrict__ rowptr, const int* __restrict__ boff,
    const int* __restrict__ csrc, const float* __restrict__ cnrm,
    const float* __restrict__ sbuf, const float* __restrict__ c2b,
    float* __restrict__ out) {
  int n = blockIdx.x * 16 + (threadIdx.x >> 4);
  int c = threadIdx.x & 15;
  if (n >= N_NODES) return;
  int r0 = RP(rowptr, boff, n), r1 = RP(rowptr, boff, n + 1);
  float a = 0.f;
  for (int j = r0 + c; j < r1; j += 16) a = fmaf(cnrm[j], sbuf[csrc[j]], a);
  a += __shfl_xor(a, 1, 16);
  a += __shfl_xor(a, 2, 16);
  a += __shfl_xor(a, 4, 16);
  a += __shfl_xor(a, 8, 16);
  if (c == 0) out[n] = a + c2b[0];
}

// ---------------------------------------------------------------------------
extern "C" void kernel_launch(void* const* d_in, const int* in_sizes, int n_in,
                              void* d_out, int out_size, void* d_ws,
                              size_t ws_size, hipStream_t stream) {
  const float* nf   = (const float*)d_in[0];
  const float* ef0  = (const float*)d_in[1];
  const float* ef1  = (const float*)d_in[2];
  const float* n_w0 = (const float*)d_in[3];  const float* n_b0 = (const float*)d_in[4];
  const float* n_w1 = (const float*)d_in[5];  const float* n_b1 = (const float*)d_in[6];
  const float* n_w2 = (const float*)d_in[7];  const float* n_b2 = (const float*)d_in[8];
  const float* e0w0 = (const float*)d_in[9];  const float* e0b0 = (const float*)d_in[10];
  const float* e0w1 = (const float*)d_in[11]; const float* e0b1 = (const float*)d_in[12];
  const float* e0w2 = (const float*)d_in[13]; const float* e0b2 = (const float*)d_in[14];
  const float* e1w0 = (const float*)d_in[15]; const float* e1b0 = (const float*)d_in[16];
  const float* e1w1 = (const float*)d_in[17]; const float* e1b1 = (const float*)d_in[18];
  const float* e1w2 = (const float*)d_in[19]; const float* e1b2 = (const float*)d_in[20];
  const float* c1w  = (const float*)d_in[21]; const float* c1b  = (const float*)d_in[22];
  const float* c2w  = (const float*)d_in[23]; const float* c2b  = (const float*)d_in[24];
  const int* src = (const int*)d_in[25];
  const int* dst = (const int*)d_in[26];
  float* out = (float*)d_out;
  float* ws = (float*)d_ws;

  // ---- workspace layout (4B units) ----
  float*  hn     = ws;                        // 3,200,000
  float*  sbuf   = ws + 3200000;              // 50,000
  int*    rowptr = (int*)(ws + 3250000);      // 50,001
  int*    cntI   = (int*)(ws + 3300008);      // 50,000 (cntI,cntO,fill contiguous)
  int*    cntO   = (int*)(ws + 3350008);      // 50,000
  int*    fill   = (int*)(ws + 3400008);      // 50,000
  int*    bsum   = (int*)(ws + 3450008);      // 256
  int*    boff   = (int*)(ws + 3450264);      // 256
  int*    eslot  = (int*)(ws + 3460000);      // 800,000
  int*    csrc   = (int*)(ws + 4260000);      // 800,000
  float*  cnrm   = ws + 5060000;              // 800,000
  float*  nmE    = ws + 5860000;              // 800,000
  ushort* msg    = (ushort*)(ws + 6660000);   // 51.2M ushorts = 25.6M floats
  ushort* pk     = (ushort*)(ws + 32260000);  // 30,720 ushorts
  // end ~32.28M floats = 129 MB

  const int NB  = (N_NODES + 255) / 256;  // 196
  const int NBn = (N_NODES + 63) / 64;    // 782
  const int NB0 = (NE0 + 63) / 64;        // 7813
  const int NB1 = (NE1 + 63) / 64;        // 4688
  const int NBc = (NE + 255) / 256;       // 3126

  hipMemsetAsync(cntI, 0, (size_t)3 * N_NODES * sizeof(int), stream);
  prep_k<<<60 + NBc, 256, 0, stream>>>(e0w0, e0w1, e0w2, e1w0, e1w1, e1w2,
                                       n_w0, n_w1, n_w2, pk, src, dst, cntO,
                                       cntI);
  scan1_k<<<NB, 256, 0, stream>>>(cntI, rowptr, bsum);
  scan2_k<<<1, 256, 0, stream>>>(bsum, boff, NB);
  scatter_k<<<NBc, 256, 0, stream>>>(src, dst, rowptr, boff, fill, cntO, cntI,
                                     eslot, csrc, cnrm, nmE);
  mega_mfma_k<<<NBn + NB0 + NB1, 256, 0, stream>>>(
      nf, ef0, ef1, pk, n_b0, n_b1, n_b2, e0b0, e0b1, e0b2, e1b0, e1b1, e1b2,
      eslot, nmE, msg, hn, NBn, NB0);
  gather_conv1_k<<<(N_NODES + 3) / 4, 256, 0, stream>>>(
      rowptr, boff, csrc, cnrm, msg, hn, c1w, c1b, c2w, sbuf);
  conv2_gather_k<<<(N_NODES + 15) / 16, 256, 0, stream>>>(
      rowptr, boff, csrc, cnrm, sbuf, c2b, out);
}

// Round 8
// 246.618 us; speedup vs baseline: 58.3974x; 1.1730x over previous
//
#include <hip/hip_runtime.h>

#define N_NODES 50000
#define NE0 500000
#define NE1 300000
#define NE (NE0 + NE1)
#define DD 64

typedef __bf16 bf16x8 __attribute__((ext_vector_type(8)));
typedef float f32x4 __attribute__((ext_vector_type(4)));

__device__ __forceinline__ ushort f2bf(float x) {  // RNE via native cvt
  union { __bf16 h; ushort u; } v;
  v.h = (__bf16)x;
  return v.u;
}
__device__ __forceinline__ float bf2f(ushort u) {
  union { unsigned u; float f; } v;
  v.u = ((unsigned)u) << 16;
  return v.f;
}

// rowptr finalization: scan1 leaves per-block partial sums, boff[b] is the
// block offset. Inline instead of a 50K-thread fixup dispatch.
__device__ __forceinline__ int RP(const int* __restrict__ rowptr,
                                  const int* __restrict__ boff, int i) {
  return (i >= N_NODES) ? NE : rowptr[i] + boff[i >> 8];
}

// ==================== fused pack(60) + count(3126) =========================
__global__ void prep_k(const float* __restrict__ w00, const float* __restrict__ w01,
                       const float* __restrict__ w02, const float* __restrict__ w10,
                       const float* __restrict__ w11, const float* __restrict__ w12,
                       const float* __restrict__ w20, const float* __restrict__ w21,
                       const float* __restrict__ w22, ushort* __restrict__ pk,
                       const int* __restrict__ src, const int* __restrict__ dst,
                       int* __restrict__ cntO, int* __restrict__ cntI) {
  int bid = blockIdx.x, tid = threadIdx.x;
  if (bid < 60) {
    if (tid >= 64) return;
    int t = bid / 20, fl = bid % 20, l = tid;
    int layer, nt, ks;
    if (fl < 4) { layer = 0; nt = fl; ks = 0; }
    else if (fl < 12) { layer = 1; nt = (fl - 4) >> 1; ks = (fl - 4) & 1; }
    else { layer = 2; nt = (fl - 12) >> 1; ks = (fl - 12) & 1; }
    const float* Wt[3][3] = {{w00, w01, w02}, {w10, w11, w12}, {w20, w21, w22}};
    const int K0[3] = {16, 8, 32};
    const float* W = Wt[t][layer];
    int K = (layer == 0) ? K0[t] : 64;
    int g = l >> 4, c = l & 15;
    ushort o[8];
#pragma unroll
    for (int e = 0; e < 8; ++e) {
      int k = ks * 32 + g * 8 + e, n = nt * 16 + c;
      o[e] = f2bf((k < K) ? W[k * DD + n] : 0.f);
    }
    ushort4* d4 = (ushort4*)&pk[(size_t)bid * 512 + l * 8];
    d4[0] = make_ushort4(o[0], o[1], o[2], o[3]);
    d4[1] = make_ushort4(o[4], o[5], o[6], o[7]);
  } else {
    int e = (bid - 60) * 256 + tid;
    if (e < NE) {
      atomicAdd(cntO + src[e], 1);
      atomicAdd(cntI + dst[e], 1);
    }
  }
}

// ============================ scans ========================================
__device__ __forceinline__ int block_scan_excl(int x, int tid, int* total) {
  int lane = tid & 63, w = tid >> 6;
  int incl = x;
#pragma unroll
  for (int d = 1; d < 64; d <<= 1) {
    int y = __shfl_up(incl, d);
    if (lane >= d) incl += y;
  }
  __shared__ int wsum[4];
  if (lane == 63) wsum[w] = incl;
  __syncthreads();
  int woff = 0;
  if (w > 0) woff = wsum[0];
  if (w > 1) woff += wsum[1];
  if (w > 2) woff += wsum[2];
  *total = wsum[0] + wsum[1] + wsum[2] + wsum[3];
  return woff + incl - x;
}

__global__ __launch_bounds__(256) void scan1_k(const int* __restrict__ cnt,
                                               int* __restrict__ rowptr,
                                               int* __restrict__ bsum) {
  int i = blockIdx.x * 256 + threadIdx.x;
  int x = (i < N_NODES) ? cnt[i] : 0;
  int tot;
  int ex = block_scan_excl(x, threadIdx.x, &tot);
  if (i < N_NODES) rowptr[i] = ex;
  if (threadIdx.x == 0) bsum[blockIdx.x] = tot;
}

__global__ __launch_bounds__(256) void scan2_k(const int* __restrict__ bsum,
                                               int* __restrict__ boff, int nb) {
  int i = threadIdx.x;
  int x = (i < nb) ? bsum[i] : 0;
  int tot;
  int ex = block_scan_excl(x, i, &tot);
  if (i < nb) boff[i] = ex;
}

__global__ void scatter_k(const int* __restrict__ src, const int* __restrict__ dst,
                          const int* __restrict__ rowptr, const int* __restrict__ boff,
                          int* __restrict__ fill, const int* __restrict__ cntO,
                          const int* __restrict__ cntI, int* __restrict__ eslot,
                          int* __restrict__ csrc, float* __restrict__ cnrm,
                          float* __restrict__ nmE) {
  int e = blockIdx.x * 256 + threadIdx.x;
  if (e < NE) {
    int s = src[e], d = dst[e];
    int slot = RP(rowptr, boff, d) + atomicAdd(fill + d, 1);
    float nm = rsqrtf((float)max(cntO[s], 1) * (float)max(cntI[d], 1));
    eslot[e] = slot;
    nmE[e] = nm;   // per-edge, coalesced for the mega kernel
    csrc[slot] = s;
    cnrm[slot] = nm;
  }
}

// ================= mega MFMA kernel: node MLP + both edge MLPs =============
// Per wave: 16 rows, fully independent (zero __syncthreads).
// A-frag: lane l holds A[m=l&15][k=(l>>4)*8+i] from per-wave LDS [16][72] bf16.
// B-frag: pre-packed stream (L1-resident). D-frag: lane l holds
// D[m=(l>>4)*4+r][n=nt*16+(l&15)] (m89-verified map).
template <int FIN, bool NODE>
__device__ __forceinline__ void mlp_body(
    ushort (*__restrict__ A)[72], const float* __restrict__ xin,
    const ushort* __restrict__ pk, int pkb, const float* __restrict__ B0,
    const float* __restrict__ B1, const float* __restrict__ B2,
    const int* __restrict__ eslot, const float* __restrict__ nmE,
    ushort* __restrict__ msg, float* __restrict__ hn, int r0w, int nR,
    int ebase) {
  const int l = threadIdx.x & 63;
  const int g = l >> 4, c = l & 15;

  // ---- stage 16 input rows (bf16), coalesced ----
  {
    int row = l >> 2;
    int r = r0w + row;
    if (FIN == 32) {
      int cq = (l & 3) * 8;
      float4 v0 = make_float4(0.f, 0.f, 0.f, 0.f), v1 = v0;
      if (r < nR) {
        v0 = *(const float4*)(xin + (size_t)r * 32 + cq);
        v1 = *(const float4*)(xin + (size_t)r * 32 + cq + 4);
      }
      *(ushort4*)&A[row][cq] = make_ushort4(f2bf(v0.x), f2bf(v0.y), f2bf(v0.z), f2bf(v0.w));
      *(ushort4*)&A[row][cq + 4] = make_ushort4(f2bf(v1.x), f2bf(v1.y), f2bf(v1.z), f2bf(v1.w));
    } else if (FIN == 16) {
      int cq = (l & 3) * 4;
      float4 v = make_float4(0.f, 0.f, 0.f, 0.f);
      if (r < nR) v = *(const float4*)(xin + (size_t)r * 16 + cq);
      *(ushort4*)&A[row][cq] = make_ushort4(f2bf(v.x), f2bf(v.y), f2bf(v.z), f2bf(v.w));
    } else {
      int cq = (l & 3) * 2;
      float2 v = make_float2(0.f, 0.f);
      if (r < nR) v = *(const float2*)(xin + (size_t)r * 8 + cq);
      *(ushort2*)&A[row][cq] = make_ushort2(f2bf(v.x), f2bf(v.y));
    }
  }
  // ---- per-row meta in lanes 0..15 (edges only) ----
  int slv = 0;
  float nmv = 0.f;
  if (!NODE && l < 16) {
    int e = r0w + l;
    if (e < nR) {
      slv = eslot[ebase + e];
      nmv = nmE[ebase + e];
    }
  }
  asm volatile("s_waitcnt lgkmcnt(0)" ::: "memory");  // same-wave LDS RAW

  f32x4 acc[4];
  // ===== L1 (K padded to 32) =====
#pragma unroll
  for (int nt = 0; nt < 4; ++nt) {
    float b = B0[nt * 16 + c];
    acc[nt] = f32x4{b, b, b, b};
  }
  {
    bf16x8 a0 = {};
    if (g * 8 < FIN) a0 = *(const bf16x8*)&A[c][g * 8];
#pragma unroll
    for (int nt = 0; nt < 4; ++nt) {
      bf16x8 bb = *(const bf16x8*)&pk[(size_t)(pkb + nt) * 512 + l * 8];
      acc[nt] = __builtin_amdgcn_mfma_f32_16x16x32_bf16(a0, bb, acc[nt], 0, 0, 0);
    }
  }
#pragma unroll
  for (int nt = 0; nt < 4; ++nt)
#pragma unroll
    for (int r = 0; r < 4; ++r)
      A[g * 4 + r][nt * 16 + c] = f2bf(fmaxf(acc[nt][r], 0.f));
  asm volatile("s_waitcnt lgkmcnt(0)" ::: "memory");

  // ===== L2 (K=64) =====
#pragma unroll
  for (int nt = 0; nt < 4; ++nt) {
    float b = B1[nt * 16 + c];
    acc[nt] = f32x4{b, b, b, b};
  }
  {
    bf16x8 x0 = *(const bf16x8*)&A[c][g * 8];
    bf16x8 x1 = *(const bf16x8*)&A[c][32 + g * 8];
#pragma unroll
    for (int nt = 0; nt < 4; ++nt) {
      bf16x8 bb0 = *(const bf16x8*)&pk[(size_t)(pkb + 4 + nt * 2) * 512 + l * 8];
      bf16x8 bb1 = *(const bf16x8*)&pk[(size_t)(pkb + 5 + nt * 2) * 512 + l * 8];
      acc[nt] = __builtin_amdgcn_mfma_f32_16x16x32_bf16(x0, bb0, acc[nt], 0, 0, 0);
      acc[nt] = __builtin_amdgcn_mfma_f32_16x16x32_bf16(x1, bb1, acc[nt], 0, 0, 0);
    }
  }
#pragma unroll
  for (int nt = 0; nt < 4; ++nt)
#pragma unroll
    for (int r = 0; r < 4; ++r)
      A[g * 4 + r][nt * 16 + c] = f2bf(fmaxf(acc[nt][r], 0.f));
  asm volatile("s_waitcnt lgkmcnt(0)" ::: "memory");

  // ===== L3 (K=64, no relu) =====
#pragma unroll
  for (int nt = 0; nt < 4; ++nt) {
    float b = B2[nt * 16 + c];
    acc[nt] = f32x4{b, b, b, b};
  }
  {
    bf16x8 x0 = *(const bf16x8*)&A[c][g * 8];
    bf16x8 x1 = *(const bf16x8*)&A[c][32 + g * 8];
#pragma unroll
    for (int nt = 0; nt < 4; ++nt) {
      bf16x8 bb0 = *(const bf16x8*)&pk[(size_t)(pkb + 12 + nt * 2) * 512 + l * 8];
      bf16x8 bb1 = *(const bf16x8*)&pk[(size_t)(pkb + 13 + nt * 2) * 512 + l * 8];
      acc[nt] = __builtin_amdgcn_mfma_f32_16x16x32_bf16(x0, bb0, acc[nt], 0, 0, 0);
      acc[nt] = __builtin_amdgcn_mfma_f32_16x16x32_bf16(x1, bb1, acc[nt], 0, 0, 0);
    }
  }

  // ===== epilogue: D-frag direct =====
  if (NODE) {
#pragma unroll
    for (int r = 0; r < 4; ++r) {
      int n = r0w + g * 4 + r;
      if (n < nR) {
        float* hp = hn + (size_t)n * DD + c;
#pragma unroll
        for (int nt = 0; nt < 4; ++nt) hp[nt * 16] = acc[nt][r];
      }
    }
  } else {
    int slot4[4];
    float nm4[4];
#pragma unroll
    for (int r = 0; r < 4; ++r) {
      int rr = g * 4 + r;
      slot4[r] = __shfl(slv, rr);
      nm4[r] = __shfl(nmv, rr);
    }
#pragma unroll
    for (int r = 0; r < 4; ++r) {
      if (r0w + g * 4 + r < nR) {
        ushort* mp = msg + (size_t)slot4[r] * DD + c;
#pragma unroll
        for (int nt = 0; nt < 4; ++nt) mp[nt * 16] = f2bf(acc[nt][r] * nm4[r]);
      }
    }
  }
}

__global__ __launch_bounds__(256, 6) void mega_mfma_k(
    const float* __restrict__ nf, const float* __restrict__ ef0,
    const float* __restrict__ ef1, const ushort* __restrict__ pk,
    const float* __restrict__ nb0, const float* __restrict__ nb1,
    const float* __restrict__ nb2, const float* __restrict__ b00,
    const float* __restrict__ b01, const float* __restrict__ b02,
    const float* __restrict__ b10, const float* __restrict__ b11,
    const float* __restrict__ b12, const int* __restrict__ eslot,
    const float* __restrict__ nmE, ushort* __restrict__ msg,
    float* __restrict__ hn, int NBn, int NB0v) {
  __shared__ __align__(16) ushort act[4][16][72];
  int bid = blockIdx.x, wid = threadIdx.x >> 6;
  ushort (*A)[72] = act[wid];
  if (bid < NBn) {
    mlp_body<32, true>(A, nf, pk, 40, nb0, nb1, nb2, nullptr, nullptr,
                       nullptr, hn, bid * 64 + wid * 16, N_NODES, 0);
  } else if (bid < NBn + NB0v) {
    mlp_body<16, false>(A, ef0, pk, 0, b00, b01, b02, eslot, nmE, msg,
                        nullptr, (bid - NBn) * 64 + wid * 16, NE0, 0);
  } else {
    mlp_body<8, false>(A, ef1, pk, 20, b10, b11, b12, eslot, nmE, msg,
                       nullptr, (bid - NBn - NB0v) * 64 + wid * 16, NE1, NE0);
  }
}

// ======================= wide streaming gather + conv1 =====================
// Wave = node. g=lane>>4 selects one of 4 CSR rows in flight, c=lane&15 owns
// a 4-feature quad. Loads: ushort4 msg (8B) + float4 hn (16B), x2 unroll ->
// 8 rows / 16 wide loads outstanding (vs 2 narrow before). Group partials
// reduced with shfl_xor(16|32).
__global__ __launch_bounds__(256) void gather_conv1_k(
    const int* __restrict__ rowptr, const int* __restrict__ boff,
    const int* __restrict__ csrc, const float* __restrict__ cnrm,
    const ushort* __restrict__ msgb, const float* __restrict__ hn,
    const float* __restrict__ c1w, const float* __restrict__ c1b,
    const float* __restrict__ c2w, float* __restrict__ sbuf) {
  int w = threadIdx.x >> 6, l = threadIdx.x & 63;
  int g = l >> 4, c = l & 15;
  int n = blockIdx.x * 4 + w;
  if (n >= N_NODES) return;
  int r0 = RP(rowptr, boff, n), r1 = RP(rowptr, boff, n + 1);
  float a0 = 0.f, a1 = 0.f, a2 = 0.f, a3 = 0.f, sn = 0.f;
  for (int j0 = r0; j0 < r1; j0 += 8) {
    int ja = j0 + g, jb = j0 + 4 + g;
    bool va = ja < r1, vb = jb < r1;
    int jas = va ? ja : r0, jbs = vb ? jb : r0;
    int sa = csrc[jas], sb = csrc[jbs];
    float na = va ? cnrm[jas] : 0.f;
    float nb = vb ? cnrm[jbs] : 0.f;
    ushort4 ma = *(const ushort4*)(msgb + (size_t)jas * DD + c * 4);
    float4 hav = *(const float4*)(hn + (size_t)sa * DD + c * 4);
    ushort4 mb = *(const ushort4*)(msgb + (size_t)jbs * DD + c * 4);
    float4 hbv = *(const float4*)(hn + (size_t)sb * DD + c * 4);
    float fa = va ? 1.f : 0.f, fb = vb ? 1.f : 0.f;
    a0 += fa * bf2f(ma.x) + fb * bf2f(mb.x);
    a1 += fa * bf2f(ma.y) + fb * bf2f(mb.y);
    a2 += fa * bf2f(ma.z) + fb * bf2f(mb.z);
    a3 += fa * bf2f(ma.w) + fb * bf2f(mb.w);
    a0 = fmaf(na, hav.x, fmaf(nb, hbv.x, a0));
    a1 = fmaf(na, hav.y, fmaf(nb, hbv.y, a1));
    a2 = fmaf(na, hav.z, fmaf(nb, hbv.z, a2));
    a3 = fmaf(na, hav.w, fmaf(nb, hbv.w, a3));
    sn += na + nb;
  }
  // reduce the 4 row-groups (lanes differing in bits 4,5)
  a0 += __shfl_xor(a0, 16); a0 += __shfl_xor(a0, 32);
  a1 += __shfl_xor(a1, 16); a1 += __shfl_xor(a1, 32);
  a2 += __shfl_xor(a2, 16); a2 += __shfl_xor(a2, 32);
  a3 += __shfl_xor(a3, 16); a3 += __shfl_xor(a3, 32);
  sn += __shfl_xor(sn, 16); sn += __shfl_xor(sn, 32);
  // + (sum nm) * hn[n]
  float4 hv = *(const float4*)(hn + (size_t)n * DD + c * 4);
  a0 = fmaf(sn, hv.x, a0);
  a1 = fmaf(sn, hv.y, a1);
  a2 = fmaf(sn, hv.z, a2);
  a3 = fmaf(sn, hv.w, a3);
  __shared__ float Asm[4][64];
  if (g == 0) *(float4*)&Asm[w][c * 4] = make_float4(a0, a1, a2, a3);
  // wave-local LDS RAW (HW-proven pattern, rounds 3-7)
  float h = c1b[l];
#pragma unroll 8
  for (int k = 0; k < 64; ++k) h = fmaf(Asm[w][k], c1w[k * DD + l], h);
  h = fmaxf(h, 0.f);
  float v = h * c2w[l];
#pragma unroll
  for (int d = 32; d; d >>= 1) v += __shfl_xor(v, d);
  if (l == 0) sbuf[n] = v;
}

// conv2: 16 lanes per node -> parallel loads instead of serial dependent.
__global__ __launch_bounds__(256) void conv2_gather_k(
    const int* __restrict__ rowptr, const int* __restrict__ boff,
    const int* __restrict__ csrc, const float* __restrict__ cnrm,
    const float* __restrict__ sbuf, const float* __restrict__ c2b,
    float* __restrict__ out) {
  int n = blockIdx.x * 16 + (threadIdx.x >> 4);
  int c = threadIdx.x & 15;
  if (n >= N_NODES) return;
  int r0 = RP(rowptr, boff, n), r1 = RP(rowptr, boff, n + 1);
  float a = 0.f;
  for (int j = r0 + c; j < r1; j += 16) a = fmaf(cnrm[j], sbuf[csrc[j]], a);
  a += __shfl_xor(a, 1, 16);
  a += __shfl_xor(a, 2, 16);
  a += __shfl_xor(a, 4, 16);
  a += __shfl_xor(a, 8, 16);
  if (c == 0) out[n] = a + c2b[0];
}

// ---------------------------------------------------------------------------
extern "C" void kernel_launch(void* const* d_in, const int* in_sizes, int n_in,
                              void* d_out, int out_size, void* d_ws,
                              size_t ws_size, hipStream_t stream) {
  const float* nf   = (const float*)d_in[0];
  const float* ef0  = (const float*)d_in[1];
  const float* ef1  = (const float*)d_in[2];
  const float* n_w0 = (const float*)d_in[3];  const float* n_b0 = (const float*)d_in[4];
  const float* n_w1 = (const float*)d_in[5];  const float* n_b1 = (const float*)d_in[6];
  const float* n_w2 = (const float*)d_in[7];  const float* n_b2 = (const float*)d_in[8];
  const float* e0w0 = (const float*)d_in[9];  const float* e0b0 = (const float*)d_in[10];
  const float* e0w1 = (const float*)d_in[11]; const float* e0b1 = (const float*)d_in[12];
  const float* e0w2 = (const float*)d_in[13]; const float* e0b2 = (const float*)d_in[14];
  const float* e1w0 = (const float*)d_in[15]; const float* e1b0 = (const float*)d_in[16];
  const float* e1w1 = (const float*)d_in[17]; const float* e1b1 = (const float*)d_in[18];
  const float* e1w2 = (const float*)d_in[19]; const float* e1b2 = (const float*)d_in[20];
  const float* c1w  = (const float*)d_in[21]; const float* c1b  = (const float*)d_in[22];
  const float* c2w  = (const float*)d_in[23]; const float* c2b  = (const float*)d_in[24];
  const int* src = (const int*)d_in[25];
  const int* dst = (const int*)d_in[26];
  float* out = (float*)d_out;
  float* ws = (float*)d_ws;

  // ---- workspace layout (4B units) ----
  float*  hn     = ws;                        // 3,200,000
  float*  sbuf   = ws + 3200000;              // 50,000
  int*    rowptr = (int*)(ws + 3250000);      // 50,001
  int*    cntI   = (int*)(ws + 3300008);      // 50,000 (cntI,cntO,fill contiguous)
  int*    cntO   = (int*)(ws + 3350008);      // 50,000
  int*    fill   = (int*)(ws + 3400008);      // 50,000
  int*    bsum   = (int*)(ws + 3450008);      // 256
  int*    boff   = (int*)(ws + 3450264);      // 256
  int*    eslot  = (int*)(ws + 3460000);      // 800,000
  int*    csrc   = (int*)(ws + 4260000);      // 800,000
  float*  cnrm   = ws + 5060000;              // 800,000
  float*  nmE    = ws + 5860000;              // 800,000
  ushort* msg    = (ushort*)(ws + 6660000);   // 51.2M ushorts = 25.6M floats
  ushort* pk     = (ushort*)(ws + 32260000);  // 30,720 ushorts
  // end ~32.28M floats = 129 MB

  const int NB  = (N_NODES + 255) / 256;  // 196
  const int NBn = (N_NODES + 63) / 64;    // 782
  const int NB0 = (NE0 + 63) / 64;        // 7813
  const int NB1 = (NE1 + 63) / 64;        // 4688
  const int NBc = (NE + 255) / 256;       // 3126

  hipMemsetAsync(cntI, 0, (size_t)3 * N_NODES * sizeof(int), stream);
  prep_k<<<60 + NBc, 256, 0, stream>>>(e0w0, e0w1, e0w2, e1w0, e1w1, e1w2,
                                       n_w0, n_w1, n_w2, pk, src, dst, cntO,
                                       cntI);
  scan1_k<<<NB, 256, 0, stream>>>(cntI, rowptr, bsum);
  scan2_k<<<1, 256, 0, stream>>>(bsum, boff, NB);
  scatter_k<<<NBc, 256, 0, stream>>>(src, dst, rowptr, boff, fill, cntO, cntI,
                                     eslot, csrc, cnrm, nmE);
  mega_mfma_k<<<NBn + NB0 + NB1, 256, 0, stream>>>(
      nf, ef0, ef1, pk, n_b0, n_b1, n_b2, e0b0, e0b1, e0b2, e1b0, e1b1, e1b2,
      eslot, nmE, msg, hn, NBn, NB0);
  gather_conv1_k<<<(N_NODES + 3) / 4, 256, 0, stream>>>(
      rowptr, boff, csrc, cnrm, msg, hn, c1w, c1b, c2w, sbuf);
  conv2_gather_k<<<(N_NODES + 15) / 16, 256, 0, stream>>>(
      rowptr, boff, csrc, cnrm, sbuf, c2b, out);
}

// Round 9
// 232.155 us; speedup vs baseline: 62.0355x; 1.0623x over previous
//
#include <hip/hip_runtime.h>

#define N_NODES 50000
#define NE0 500000
#define NE1 300000
#define NE (NE0 + NE1)
#define DD 64

typedef __bf16 bf16x8 __attribute__((ext_vector_type(8)));
typedef float f32x4 __attribute__((ext_vector_type(4)));
typedef unsigned short u16x8 __attribute__((ext_vector_type(8)));

__device__ __forceinline__ ushort f2bf(float x) {  // RNE via native cvt
  union { __bf16 h; ushort u; } v;
  v.h = (__bf16)x;
  return v.u;
}
__device__ __forceinline__ float bf2f(ushort u) {
  union { unsigned u; float f; } v;
  v.u = ((unsigned)u) << 16;
  return v.f;
}

// rowptr finalization: scan1 leaves per-block partials, boff[b] block offset.
__device__ __forceinline__ int RP(const int* __restrict__ rowptr,
                                  const int* __restrict__ boff, int i) {
  return (i >= N_NODES) ? NE : rowptr[i] + boff[i >> 8];
}

// ==================== fused pack(60) + count(3126) =========================
__global__ void prep_k(const float* __restrict__ w00, const float* __restrict__ w01,
                       const float* __restrict__ w02, const float* __restrict__ w10,
                       const float* __restrict__ w11, const float* __restrict__ w12,
                       const float* __restrict__ w20, const float* __restrict__ w21,
                       const float* __restrict__ w22, ushort* __restrict__ pk,
                       const int* __restrict__ src, const int* __restrict__ dst,
                       int* __restrict__ cntO, int* __restrict__ cntI) {
  int bid = blockIdx.x, tid = threadIdx.x;
  if (bid < 60) {
    if (tid >= 64) return;
    int t = bid / 20, fl = bid % 20, l = tid;
    int layer, nt, ks;
    if (fl < 4) { layer = 0; nt = fl; ks = 0; }
    else if (fl < 12) { layer = 1; nt = (fl - 4) >> 1; ks = (fl - 4) & 1; }
    else { layer = 2; nt = (fl - 12) >> 1; ks = (fl - 12) & 1; }
    const float* Wt[3][3] = {{w00, w01, w02}, {w10, w11, w12}, {w20, w21, w22}};
    const int K0[3] = {16, 8, 32};
    const float* W = Wt[t][layer];
    int K = (layer == 0) ? K0[t] : 64;
    int g = l >> 4, c = l & 15;
    ushort o[8];
#pragma unroll
    for (int e = 0; e < 8; ++e) {
      int k = ks * 32 + g * 8 + e, n = nt * 16 + c;
      o[e] = f2bf((k < K) ? W[k * DD + n] : 0.f);
    }
    ushort4* d4 = (ushort4*)&pk[(size_t)bid * 512 + l * 8];
    d4[0] = make_ushort4(o[0], o[1], o[2], o[3]);
    d4[1] = make_ushort4(o[4], o[5], o[6], o[7]);
  } else {
    int e = (bid - 60) * 256 + tid;
    if (e < NE) {
      atomicAdd(cntO + src[e], 1);
      atomicAdd(cntI + dst[e], 1);
    }
  }
}

// ============================ scans ========================================
__device__ __forceinline__ int block_scan_excl(int x, int tid, int* total) {
  int lane = tid & 63, w = tid >> 6;
  int incl = x;
#pragma unroll
  for (int d = 1; d < 64; d <<= 1) {
    int y = __shfl_up(incl, d);
    if (lane >= d) incl += y;
  }
  __shared__ int wsum[4];
  if (lane == 63) wsum[w] = incl;
  __syncthreads();
  int woff = 0;
  if (w > 0) woff = wsum[0];
  if (w > 1) woff += wsum[1];
  if (w > 2) woff += wsum[2];
  *total = wsum[0] + wsum[1] + wsum[2] + wsum[3];
  return woff + incl - x;
}

__global__ __launch_bounds__(256) void scan1_k(const int* __restrict__ cnt,
                                               int* __restrict__ rowptr,
                                               int* __restrict__ bsum) {
  int i = blockIdx.x * 256 + threadIdx.x;
  int x = (i < N_NODES) ? cnt[i] : 0;
  int tot;
  int ex = block_scan_excl(x, threadIdx.x, &tot);
  if (i < N_NODES) rowptr[i] = ex;
  if (threadIdx.x == 0) bsum[blockIdx.x] = tot;
}

__global__ __launch_bounds__(256) void scan2_k(const int* __restrict__ bsum,
                                               int* __restrict__ boff, int nb) {
  int i = threadIdx.x;
  int x = (i < nb) ? bsum[i] : 0;
  int tot;
  int ex = block_scan_excl(x, i, &tot);
  if (i < nb) boff[i] = ex;
}

__global__ void scatter_k(const int* __restrict__ src, const int* __restrict__ dst,
                          const int* __restrict__ rowptr, const int* __restrict__ boff,
                          int* __restrict__ fill, const int* __restrict__ cntO,
                          const int* __restrict__ cntI, int* __restrict__ eslot,
                          int* __restrict__ csrc, float* __restrict__ cnrm,
                          float* __restrict__ nmE) {
  int e = blockIdx.x * 256 + threadIdx.x;
  if (e < NE) {
    int s = src[e], d = dst[e];
    int slot = RP(rowptr, boff, d) + atomicAdd(fill + d, 1);
    float nm = rsqrtf((float)max(cntO[s], 1) * (float)max(cntI[d], 1));
    eslot[e] = slot;
    nmE[e] = nm;
    csrc[slot] = s;
    cnrm[slot] = nm;
  }
}

// ================= mega MFMA kernel: node MLP + both edge MLPs =============
// M=32 rows per wave (2 m-tiles share every B-frag load). Zero __syncthreads.
// A-frag: lane l holds A[m=l&15][k=(l>>4)*8+i] from per-wave LDS [32][72] bf16.
// D-frag: lane l holds D[m=(l>>4)*4+r][n=nt*16+(l&15)] (m89-verified map).
// Edge epilogue: nm*he parked in A (row-major bf16), then 4x {ds_read_b128 +
// 16B global store} = full-128B-segment scatter (vs 32x16 2B stores).
template <int FIN, bool NODE>
__device__ __forceinline__ void mlp_body(
    ushort (*__restrict__ A)[72], const float* __restrict__ xin,
    const ushort* __restrict__ pk, int pkb, const float* __restrict__ B0,
    const float* __restrict__ B1, const float* __restrict__ B2,
    const int* __restrict__ eslot, const float* __restrict__ nmE,
    ushort* __restrict__ msg, float* __restrict__ hn, int r0w, int nR,
    int ebase) {
  const int l = threadIdx.x & 63;
  const int g = l >> 4, c = l & 15;

  // ---- stage 32 input rows (bf16), coalesced: row = l>>1, half = l&1 ----
  {
    int row = l >> 1, half = l & 1;
    int r = r0w + row;
    bool ok = r < nR;
    if (FIN == 32) {
      int cq = half * 16;
#pragma unroll
      for (int q = 0; q < 4; ++q) {
        float4 v = make_float4(0.f, 0.f, 0.f, 0.f);
        if (ok) v = *(const float4*)(xin + (size_t)r * 32 + cq + q * 4);
        *(ushort4*)&A[row][cq + q * 4] =
            make_ushort4(f2bf(v.x), f2bf(v.y), f2bf(v.z), f2bf(v.w));
      }
    } else if (FIN == 16) {
      int cq = half * 8;
#pragma unroll
      for (int q = 0; q < 2; ++q) {
        float4 v = make_float4(0.f, 0.f, 0.f, 0.f);
        if (ok) v = *(const float4*)(xin + (size_t)r * 16 + cq + q * 4);
        *(ushort4*)&A[row][cq + q * 4] =
            make_ushort4(f2bf(v.x), f2bf(v.y), f2bf(v.z), f2bf(v.w));
      }
    } else {
      int cq = half * 4;
      float4 v = make_float4(0.f, 0.f, 0.f, 0.f);
      if (ok) v = *(const float4*)(xin + (size_t)r * 8 + cq);
      *(ushort4*)&A[row][cq] =
          make_ushort4(f2bf(v.x), f2bf(v.y), f2bf(v.z), f2bf(v.w));
    }
  }
  // ---- per-row meta in lanes 0..31 (edges only) ----
  int slv = 0;
  float nmv = 0.f;
  if (!NODE && l < 32) {
    int e = r0w + l;
    if (e < nR) {
      slv = eslot[ebase + e];
      nmv = nmE[ebase + e];
    }
  }
  asm volatile("s_waitcnt lgkmcnt(0)" ::: "memory");  // same-wave LDS RAW

  f32x4 acc[2][4];
  // ===== L1 (K padded to 32) =====
#pragma unroll
  for (int nt = 0; nt < 4; ++nt) {
    float b = B0[nt * 16 + c];
    acc[0][nt] = f32x4{b, b, b, b};
    acc[1][nt] = acc[0][nt];
  }
  {
    bf16x8 a0 = {}, a1 = {};
    if (g * 8 < FIN) {
      a0 = *(const bf16x8*)&A[c][g * 8];
      a1 = *(const bf16x8*)&A[16 + c][g * 8];
    }
#pragma unroll
    for (int nt = 0; nt < 4; ++nt) {
      bf16x8 bb = *(const bf16x8*)&pk[(size_t)(pkb + nt) * 512 + l * 8];
      acc[0][nt] = __builtin_amdgcn_mfma_f32_16x16x32_bf16(a0, bb, acc[0][nt], 0, 0, 0);
      acc[1][nt] = __builtin_amdgcn_mfma_f32_16x16x32_bf16(a1, bb, acc[1][nt], 0, 0, 0);
    }
  }
#pragma unroll
  for (int t = 0; t < 2; ++t)
#pragma unroll
    for (int nt = 0; nt < 4; ++nt)
#pragma unroll
      for (int r = 0; r < 4; ++r)
        A[t * 16 + g * 4 + r][nt * 16 + c] = f2bf(fmaxf(acc[t][nt][r], 0.f));
  asm volatile("s_waitcnt lgkmcnt(0)" ::: "memory");

  // ===== L2 (K=64) =====
#pragma unroll
  for (int nt = 0; nt < 4; ++nt) {
    float b = B1[nt * 16 + c];
    acc[0][nt] = f32x4{b, b, b, b};
    acc[1][nt] = acc[0][nt];
  }
  {
    bf16x8 x00 = *(const bf16x8*)&A[c][g * 8];
    bf16x8 x01 = *(const bf16x8*)&A[c][32 + g * 8];
    bf16x8 x10 = *(const bf16x8*)&A[16 + c][g * 8];
    bf16x8 x11 = *(const bf16x8*)&A[16 + c][32 + g * 8];
#pragma unroll
    for (int nt = 0; nt < 4; ++nt) {
      bf16x8 bb0 = *(const bf16x8*)&pk[(size_t)(pkb + 4 + nt * 2) * 512 + l * 8];
      bf16x8 bb1 = *(const bf16x8*)&pk[(size_t)(pkb + 5 + nt * 2) * 512 + l * 8];
      acc[0][nt] = __builtin_amdgcn_mfma_f32_16x16x32_bf16(x00, bb0, acc[0][nt], 0, 0, 0);
      acc[0][nt] = __builtin_amdgcn_mfma_f32_16x16x32_bf16(x01, bb1, acc[0][nt], 0, 0, 0);
      acc[1][nt] = __builtin_amdgcn_mfma_f32_16x16x32_bf16(x10, bb0, acc[1][nt], 0, 0, 0);
      acc[1][nt] = __builtin_amdgcn_mfma_f32_16x16x32_bf16(x11, bb1, acc[1][nt], 0, 0, 0);
    }
  }
#pragma unroll
  for (int t = 0; t < 2; ++t)
#pragma unroll
    for (int nt = 0; nt < 4; ++nt)
#pragma unroll
      for (int r = 0; r < 4; ++r)
        A[t * 16 + g * 4 + r][nt * 16 + c] = f2bf(fmaxf(acc[t][nt][r], 0.f));
  asm volatile("s_waitcnt lgkmcnt(0)" ::: "memory");

  // ===== L3 (K=64, no relu) =====
#pragma unroll
  for (int nt = 0; nt < 4; ++nt) {
    float b = B2[nt * 16 + c];
    acc[0][nt] = f32x4{b, b, b, b};
    acc[1][nt] = acc[0][nt];
  }
  {
    bf16x8 x00 = *(const bf16x8*)&A[c][g * 8];
    bf16x8 x01 = *(const bf16x8*)&A[c][32 + g * 8];
    bf16x8 x10 = *(const bf16x8*)&A[16 + c][g * 8];
    bf16x8 x11 = *(const bf16x8*)&A[16 + c][32 + g * 8];
#pragma unroll
    for (int nt = 0; nt < 4; ++nt) {
      bf16x8 bb0 = *(const bf16x8*)&pk[(size_t)(pkb + 12 + nt * 2) * 512 + l * 8];
      bf16x8 bb1 = *(const bf16x8*)&pk[(size_t)(pkb + 13 + nt * 2) * 512 + l * 8];
      acc[0][nt] = __builtin_amdgcn_mfma_f32_16x16x32_bf16(x00, bb0, acc[0][nt], 0, 0, 0);
      acc[0][nt] = __builtin_amdgcn_mfma_f32_16x16x32_bf16(x01, bb1, acc[0][nt], 0, 0, 0);
      acc[1][nt] = __builtin_amdgcn_mfma_f32_16x16x32_bf16(x10, bb0, acc[1][nt], 0, 0, 0);
      acc[1][nt] = __builtin_amdgcn_mfma_f32_16x16x32_bf16(x11, bb1, acc[1][nt], 0, 0, 0);
    }
  }

  // ===== epilogue =====
  if (NODE) {
#pragma unroll
    for (int t = 0; t < 2; ++t)
#pragma unroll
      for (int r = 0; r < 4; ++r) {
        int n = r0w + t * 16 + g * 4 + r;
        if (n < nR) {
          float* hp = hn + (size_t)n * DD + c;
#pragma unroll
          for (int nt = 0; nt < 4; ++nt) hp[nt * 16] = acc[t][nt][r];
        }
      }
  } else {
    // park bf16(nm*he) in A row-major, then wide 128B-per-row scatter
#pragma unroll
    for (int t = 0; t < 2; ++t) {
      float nm4[4];
#pragma unroll
      for (int r = 0; r < 4; ++r) nm4[r] = __shfl(nmv, t * 16 + g * 4 + r);
#pragma unroll
      for (int nt = 0; nt < 4; ++nt)
#pragma unroll
        for (int r = 0; r < 4; ++r)
          A[t * 16 + g * 4 + r][nt * 16 + c] = f2bf(acc[t][nt][r] * nm4[r]);
    }
    asm volatile("s_waitcnt lgkmcnt(0)" ::: "memory");
#pragma unroll
    for (int p = 0; p < 4; ++p) {
      int row = p * 8 + (l >> 3);
      int col8 = (l & 7) * 8;
      u16x8 v = *(const u16x8*)&A[row][col8];
      int slot = __shfl(slv, row);
      if (r0w + row < nR)
        *(u16x8*)(msg + (size_t)slot * DD + col8) = v;
    }
  }
}

__global__ __launch_bounds__(256, 6) void mega_mfma_k(
    const float* __restrict__ nf, const float* __restrict__ ef0,
    const float* __restrict__ ef1, const ushort* __restrict__ pk,
    const float* __restrict__ nb0, const float* __restrict__ nb1,
    const float* __restrict__ nb2, const float* __restrict__ b00,
    const float* __restrict__ b01, const float* __restrict__ b02,
    const float* __restrict__ b10, const float* __restrict__ b11,
    const float* __restrict__ b12, const int* __restrict__ eslot,
    const float* __restrict__ nmE, ushort* __restrict__ msg,
    float* __restrict__ hn, int NBn, int NB0v) {
  __shared__ __align__(16) ushort act[4][32][72];
  int bid = blockIdx.x, wid = threadIdx.x >> 6;
  ushort (*A)[72] = act[wid];
  if (bid < NBn) {
    mlp_body<32, true>(A, nf, pk, 40, nb0, nb1, nb2, nullptr, nullptr,
                       nullptr, hn, bid * 128 + wid * 32, N_NODES, 0);
  } else if (bid < NBn + NB0v) {
    mlp_body<16, false>(A, ef0, pk, 0, b00, b01, b02, eslot, nmE, msg,
                        nullptr, (bid - NBn) * 128 + wid * 32, NE0, 0);
  } else {
    mlp_body<8, false>(A, ef1, pk, 20, b10, b11, b12, eslot, nmE, msg,
                       nullptr, (bid - NBn - NB0v) * 128 + wid * 32, NE1, NE0);
  }
}

// ======================= wide streaming gather + conv1 =====================
__global__ __launch_bounds__(256) void gather_conv1_k(
    const int* __restrict__ rowptr, const int* __restrict__ boff,
    const int* __restrict__ csrc, const float* __restrict__ cnrm,
    const ushort* __restrict__ msgb, const float* __restrict__ hn,
    const float* __restrict__ c1w, const float* __restrict__ c1b,
    const float* __restrict__ c2w, float* __restrict__ sbuf) {
  int w = threadIdx.x >> 6, l = threadIdx.x & 63;
  int g = l >> 4, c = l & 15;
  int n = blockIdx.x * 4 + w;
  if (n >= N_NODES) return;
  int r0 = RP(rowptr, boff, n), r1 = RP(rowptr, boff, n + 1);
  float a0 = 0.f, a1 = 0.f, a2 = 0.f, a3 = 0.f, sn = 0.f;
  for (int j0 = r0; j0 < r1; j0 += 8) {
    int ja = j0 + g, jb = j0 + 4 + g;
    bool va = ja < r1, vb = jb < r1;
    int jas = va ? ja : r0, jbs = vb ? jb : r0;
    int sa = csrc[jas], sb = csrc[jbs];
    float na = va ? cnrm[jas] : 0.f;
    float nb = vb ? cnrm[jbs] : 0.f;
    ushort4 ma = *(const ushort4*)(msgb + (size_t)jas * DD + c * 4);
    float4 hav = *(const float4*)(hn + (size_t)sa * DD + c * 4);
    ushort4 mb = *(const ushort4*)(msgb + (size_t)jbs * DD + c * 4);
    float4 hbv = *(const float4*)(hn + (size_t)sb * DD + c * 4);
    float fa = va ? 1.f : 0.f, fb = vb ? 1.f : 0.f;
    a0 += fa * bf2f(ma.x) + fb * bf2f(mb.x);
    a1 += fa * bf2f(ma.y) + fb * bf2f(mb.y);
    a2 += fa * bf2f(ma.z) + fb * bf2f(mb.z);
    a3 += fa * bf2f(ma.w) + fb * bf2f(mb.w);
    a0 = fmaf(na, hav.x, fmaf(nb, hbv.x, a0));
    a1 = fmaf(na, hav.y, fmaf(nb, hbv.y, a1));
    a2 = fmaf(na, hav.z, fmaf(nb, hbv.z, a2));
    a3 = fmaf(na, hav.w, fmaf(nb, hbv.w, a3));
    sn += na + nb;
  }
  a0 += __shfl_xor(a0, 16); a0 += __shfl_xor(a0, 32);
  a1 += __shfl_xor(a1, 16); a1 += __shfl_xor(a1, 32);
  a2 += __shfl_xor(a2, 16); a2 += __shfl_xor(a2, 32);
  a3 += __shfl_xor(a3, 16); a3 += __shfl_xor(a3, 32);
  sn += __shfl_xor(sn, 16); sn += __shfl_xor(sn, 32);
  float4 hv = *(const float4*)(hn + (size_t)n * DD + c * 4);
  a0 = fmaf(sn, hv.x, a0);
  a1 = fmaf(sn, hv.y, a1);
  a2 = fmaf(sn, hv.z, a2);
  a3 = fmaf(sn, hv.w, a3);
  __shared__ float Asm[4][64];
  if (g == 0) *(float4*)&Asm[w][c * 4] = make_float4(a0, a1, a2, a3);
  float h = c1b[l];
#pragma unroll 8
  for (int k = 0; k < 64; ++k) h = fmaf(Asm[w][k], c1w[k * DD + l], h);
  h = fmaxf(h, 0.f);
  float v = h * c2w[l];
#pragma unroll
  for (int d = 32; d; d >>= 1) v += __shfl_xor(v, d);
  if (l == 0) sbuf[n] = v;
}

// conv2: 16 lanes per node, parallel loads.
__global__ __launch_bounds__(256) void conv2_gather_k(
    const int* __restrict__ rowptr, const int* __restrict__ boff,
    const int* __restrict__ csrc, const float* __restrict__ cnrm,
    const float* __restrict__ sbuf, const float* __restrict__ c2b,
    float* __restrict__ out) {
  int n = blockIdx.x * 16 + (threadIdx.x >> 4);
  int c = threadIdx.x & 15;
  if (n >= N_NODES) return;
  int r0 = RP(rowptr, boff, n), r1 = RP(rowptr, boff, n + 1);
  float a = 0.f;
  for (int j = r0 + c; j < r1; j += 16) a = fmaf(cnrm[j], sbuf[csrc[j]], a);
  a += __shfl_xor(a, 1, 16);
  a += __shfl_xor(a, 2, 16);
  a += __shfl_xor(a, 4, 16);
  a += __shfl_xor(a, 8, 16);
  if (c == 0) out[n] = a + c2b[0];
}

// ---------------------------------------------------------------------------
extern "C" void kernel_launch(void* const* d_in, const int* in_sizes, int n_in,
                              void* d_out, int out_size, void* d_ws,
                              size_t ws_size, hipStream_t stream) {
  const float* nf   = (const float*)d_in[0];
  const float* ef0  = (const float*)d_in[1];
  const float* ef1  = (const float*)d_in[2];
  const float* n_w0 = (const float*)d_in[3];  const float* n_b0 = (const float*)d_in[4];
  const float* n_w1 = (const float*)d_in[5];  const float* n_b1 = (const float*)d_in[6];
  const float* n_w2 = (const float*)d_in[7];  const float* n_b2 = (const float*)d_in[8];
  const float* e0w0 = (const float*)d_in[9];  const float* e0b0 = (const float*)d_in[10];
  const float* e0w1 = (const float*)d_in[11]; const float* e0b1 = (const float*)d_in[12];
  const float* e0w2 = (const float*)d_in[13]; const float* e0b2 = (const float*)d_in[14];
  const float* e1w0 = (const float*)d_in[15]; const float* e1b0 = (const float*)d_in[16];
  const float* e1w1 = (const float*)d_in[17]; const float* e1b1 = (const float*)d_in[18];
  const float* e1w2 = (const float*)d_in[19]; const float* e1b2 = (const float*)d_in[20];
  const float* c1w  = (const float*)d_in[21]; const float* c1b  = (const float*)d_in[22];
  const float* c2w  = (const float*)d_in[23]; const float* c2b  = (const float*)d_in[24];
  const int* src = (const int*)d_in[25];
  const int* dst = (const int*)d_in[26];
  float* out = (float*)d_out;
  float* ws = (float*)d_ws;

  // ---- workspace layout (4B units) ----
  float*  hn     = ws;                        // 3,200,000
  float*  sbuf   = ws + 3200000;              // 50,000
  int*    rowptr = (int*)(ws + 3250000);      // 50,001
  int*    cntI   = (int*)(ws + 3300008);      // 50,000 (cntI,cntO,fill contiguous)
  int*    cntO   = (int*)(ws + 3350008);      // 50,000
  int*    fill   = (int*)(ws + 3400008);      // 50,000
  int*    bsum   = (int*)(ws + 3450008);      // 256
  int*    boff   = (int*)(ws + 3450264);      // 256
  int*    eslot  = (int*)(ws + 3460000);      // 800,000
  int*    csrc   = (int*)(ws + 4260000);      // 800,000
  float*  cnrm   = ws + 5060000;              // 800,000
  float*  nmE    = ws + 5860000;              // 800,000
  ushort* msg    = (ushort*)(ws + 6660000);   // 51.2M ushorts = 25.6M floats
  ushort* pk     = (ushort*)(ws + 32260000);  // 30,720 ushorts
  // end ~32.28M floats = 129 MB

  const int NB  = (N_NODES + 255) / 256;   // 196
  const int NBn = (N_NODES + 127) / 128;   // 391
  const int NB0 = (NE0 + 127) / 128;       // 3907
  const int NB1 = (NE1 + 127) / 128;       // 2344
  const int NBc = (NE + 255) / 256;        // 3126

  hipMemsetAsync(cntI, 0, (size_t)3 * N_NODES * sizeof(int), stream);
  prep_k<<<60 + NBc, 256, 0, stream>>>(e0w0, e0w1, e0w2, e1w0, e1w1, e1w2,
                                       n_w0, n_w1, n_w2, pk, src, dst, cntO,
                                       cntI);
  scan1_k<<<NB, 256, 0, stream>>>(cntI, rowptr, bsum);
  scan2_k<<<1, 256, 0, stream>>>(bsum, boff, NB);
  scatter_k<<<NBc, 256, 0, stream>>>(src, dst, rowptr, boff, fill, cntO, cntI,
                                     eslot, csrc, cnrm, nmE);
  mega_mfma_k<<<NBn + NB0 + NB1, 256, 0, stream>>>(
      nf, ef0, ef1, pk, n_b0, n_b1, n_b2, e0b0, e0b1, e0b2, e1b0, e1b1, e1b2,
      eslot, nmE, msg, hn, NBn, NB0);
  gather_conv1_k<<<(N_NODES + 3) / 4, 256, 0, stream>>>(
      rowptr, boff, csrc, cnrm, msg, hn, c1w, c1b, c2w, sbuf);
  conv2_gather_k<<<(N_NODES + 15) / 16, 256, 0, stream>>>(
      rowptr, boff, csrc, cnrm, sbuf, c2b, out);
}